// Round 17
// baseline (149.048 us; speedup 1.0000x reference)
//
#include <hip/hip_runtime.h>
#include <hip/hip_bf16.h>

#define N_NODES 100000
#define N_EDGES 20000
#define N_PAIRS 640000
#define CH 128      // HEADS * OUT_CH
#define HEADS 4
#define MAXDV 32    // per-vertex fast-path capacity (Poisson(6.4): max ~25)

#define NG_GEMM 1563            // (N_NODES+63)/64
#define NCHUNK 125              // pair chunks (both sides)
#define ECHUNK 5120             // pairs per chunk
#define EW 5120                 // edge hist words (20480 bins @ 4x8b) = 20.48KB
#define VWR 5000                // vertex hist words per range (20000 bins @ 4x8b)
#define NRANGE 5
#define VBIN_R 20000

// ---- workspace layout (bytes), all 16B-aligned ----
#define OFF_X0H   0UL           // 25,600,000
#define OFF_XEH   25600000UL    //  5,120,000
#define OFF_LRE   30720000UL    //    640,000 u8 (edge local rank)
#define OFF_LRV5  31360000UL    //  5*640,000 u8 (vertex local rank, per range)
#define OFF_BLKE  34560000UL    // 125*5120 u32 =  2,560,000
#define OFF_BLKV  37120000UL    // 625*5000 u32 = 12,500,000
#define OFF_GSE   49620000UL    //   5*5120 u32 =    102,400
#define OFF_GSV   49722400UL    //  25*5000 u32 =    500,000
#define OFF_WT    50222400UL    //     32,768
#define OFF_ALPHA 50255168UL    //    320,000
#define OFF_OFFE  50575168UL    //     81,920 (20480 i32)
#define OFF_ENDE  50657088UL    //     81,920
#define OFF_OFFV  50739008UL    //    400,000
#define OFF_ENDV  51139008UL    //    400,000
#define OFF_PIDXE 51539008UL    //  2,560,000 (VERTEX ids, edge-grouped)
#define OFF_PIDXV 54099008UL    //  2,560,000 (EDGE ids, vertex-grouped)
#define OFF_TOT   56659008UL    //          8  } only zero region
#define ZERO_BYTES 8UL

typedef __attribute__((ext_vector_type(8))) short bf16x8;
typedef __attribute__((ext_vector_type(4))) float f32x4;

__device__ inline short f2bf(float f) {
    __hip_bfloat16 h = __float2bfloat16(f);   // RNE
    return reinterpret_cast<short&>(h);
}
__device__ inline float bflo(unsigned w) { return __uint_as_float(w << 16); }
__device__ inline float bfhi(unsigned w) { return __uint_as_float(w & 0xffff0000u); }

// ---- W prep: Wt[n][k] = bf16(W[k][n]) ----
__global__ __launch_bounds__(256) void k_wprep(const float* __restrict__ W,
                                               short* __restrict__ Wt) {
    const int idx = blockIdx.x * 256 + threadIdx.x;   // 64 * 256
    const int n = idx >> 7, k = idx & 127;
    Wt[n * CH + k] = f2bf(W[k * CH + n]);
}

// ---- gemm body: FULL-depth A prefetch (all X loads issued before any MFMA;
//      L3 latency paid once per wave, not once per k-step) ----
__device__ inline void gemm_body(int gb, const float* __restrict__ X,
                                 const short* __restrict__ Wt,
                                 short* __restrict__ X0h) {
    const int t = threadIdx.x;
    const int wave = t >> 6, lane = t & 63;
    const int r0 = gb * 64 + (wave >> 1) * 32;
    const int c0 = (wave & 1) * 64;
    const int lrow = lane & 15, lk8 = (lane >> 4) * 8;
    const int row0 = min(r0 + lrow, N_NODES - 1);
    const int row1 = min(r0 + 16 + lrow, N_NODES - 1);
    const float* px0 = &X[(size_t)row0 * CH + lk8];
    const float* px1 = &X[(size_t)row1 * CH + lk8];
    const short* pw0 = &Wt[(size_t)(c0 + lrow) * CH + lk8];

    // all 4 k-steps of A, both rows: 16 x float4 = 64 VGPR, all independent loads
    float4 xa0[4][2], xa1[4][2];
#pragma unroll
    for (int kk = 0; kk < 4; ++kk) {
        xa0[kk][0] = *(const float4*)(px0 + kk * 32);
        xa0[kk][1] = *(const float4*)(px0 + kk * 32 + 4);
        xa1[kk][0] = *(const float4*)(px1 + kk * 32);
        xa1[kk][1] = *(const float4*)(px1 + kk * 32 + 4);
    }
    bf16x8 bb[4], bn[4];
#pragma unroll
    for (int n = 0; n < 4; ++n) bb[n] = *(const bf16x8*)(pw0 + n * 16 * CH);

    f32x4 acc[2][4] = {};
#pragma unroll
    for (int kk = 0; kk < 4; ++kk) {
        if (kk < 3) {
#pragma unroll
            for (int n = 0; n < 4; ++n)
                bn[n] = *(const bf16x8*)(pw0 + n * 16 * CH + (kk + 1) * 32);
        }
        bf16x8 a[2];
        a[0][0] = f2bf(xa0[kk][0].x); a[0][1] = f2bf(xa0[kk][0].y);
        a[0][2] = f2bf(xa0[kk][0].z); a[0][3] = f2bf(xa0[kk][0].w);
        a[0][4] = f2bf(xa0[kk][1].x); a[0][5] = f2bf(xa0[kk][1].y);
        a[0][6] = f2bf(xa0[kk][1].z); a[0][7] = f2bf(xa0[kk][1].w);
        a[1][0] = f2bf(xa1[kk][0].x); a[1][1] = f2bf(xa1[kk][0].y);
        a[1][2] = f2bf(xa1[kk][0].z); a[1][3] = f2bf(xa1[kk][0].w);
        a[1][4] = f2bf(xa1[kk][1].x); a[1][5] = f2bf(xa1[kk][1].y);
        a[1][6] = f2bf(xa1[kk][1].z); a[1][7] = f2bf(xa1[kk][1].w);
#pragma unroll
        for (int m = 0; m < 2; ++m)
#pragma unroll
            for (int n = 0; n < 4; ++n)
                acc[m][n] = __builtin_amdgcn_mfma_f32_16x16x32_bf16(a[m], bb[n], acc[m][n], 0, 0, 0);
        if (kk < 3) {
#pragma unroll
            for (int n = 0; n < 4; ++n) bb[n] = bn[n];
        }
    }

    // C/D layout: col = lane&15, row = (lane>>4)*4 + reg   [m89-verified]
#pragma unroll
    for (int m = 0; m < 2; ++m) {
#pragma unroll
        for (int reg = 0; reg < 4; ++reg) {
            const int row = r0 + m * 16 + (lane >> 4) * 4 + reg;
            if (row < N_NODES) {
#pragma unroll
                for (int n = 0; n < 4; ++n)
                    X0h[(size_t)row * CH + c0 + n * 16 + (lane & 15)] = f2bf(acc[m][n][reg]);
            }
        }
    }
}

// ====== FUSED phase 1: gemm(1563) first | vcount(625) | ecount(125) ======
__global__ __launch_bounds__(256) void k_phase1(const float* __restrict__ X,
                                                const short* __restrict__ Wt,
                                                short* __restrict__ X0h,
                                                const int* __restrict__ vertex,
                                                const int* __restrict__ edges,
                                                unsigned char* __restrict__ lrank_e,
                                                unsigned char* __restrict__ lrank_v5,
                                                unsigned int* __restrict__ blkcnt_e,
                                                unsigned int* __restrict__ blkcnt_v) {
    __shared__ unsigned int hist[EW];   // 20,480 B
    const int bid = blockIdx.x;
    const int t = threadIdx.x;

    if (bid < NG_GEMM) {                // long-pole gemm blocks dispatch first
        gemm_body(bid, X, Wt, X0h);
        return;
    }
    const int r2 = bid - NG_GEMM;
    if (r2 < NRANGE * NCHUNK) {
        // ---- vcount: range r, chunk c (5,120 pairs; 20 iters -> short block) ----
        const int r = r2 % NRANGE, c = r2 / NRANGE;
        for (int i = t; i < VWR; i += 256) hist[i] = 0;
        __syncthreads();
        const int base = c * ECHUNK;
        const int vmin = r * VBIN_R;
        unsigned char* __restrict__ lr = lrank_v5 + (size_t)r * N_PAIRS;
#pragma unroll
        for (int it = 0; it < 20; ++it) {
            const int m = base + it * 256 + t;
            const int loc = vertex[m] - vmin;
            if ((unsigned)loc < (unsigned)VBIN_R) {
                const unsigned sh = (unsigned)(loc & 3) * 8u;
                unsigned old = atomicAdd(&hist[loc >> 2], 1u << sh);
                lr[m] = (unsigned char)((old >> sh) & 0xffu);
            }
        }
        __syncthreads();
        unsigned int* dst = &blkcnt_v[(size_t)(r * NCHUNK + c) * VWR];
        for (int w = t; w < VWR; w += 256) dst[w] = hist[w];
        return;
    }
    // ---- ecount: chunk c ----
    const int c = r2 - NRANGE * NCHUNK;
    for (int i = t; i < EW; i += 256) hist[i] = 0;
    __syncthreads();
    const int base = c * ECHUNK;
#pragma unroll
    for (int it = 0; it < 20; ++it) {
        const int m = base + it * 256 + t;
        const int e = edges[m];
        const unsigned sh = (unsigned)(e & 3) * 8u;
        unsigned old = atomicAdd(&hist[e >> 2], 1u << sh);
        lrank_e[m] = (unsigned char)((old >> sh) & 0xffu);
    }
    __syncthreads();
    unsigned int* dst = &blkcnt_e[(size_t)c * EW];
    for (int w = t; w < EW; w += 256) dst[w] = hist[w];
}

// ---- scan p1: group partial sums, uint4-vectorized (4 packed words/thread) ----
__global__ __launch_bounds__(256) void k_scan_p1(const unsigned int* __restrict__ blkcnt_e,
                                                 const unsigned int* __restrict__ blkcnt_v,
                                                 unsigned int* __restrict__ gse,
                                                 unsigned int* __restrict__ gsv) {
    const int bid = blockIdx.x;
    if (bid < 25) {                                   // edge: 5 groups x 1280 uint4
        const int gid = bid * 256 + threadIdx.x;      // 6400
        const int g = gid / 1280, w4 = gid % 1280;
        uint4 s = {0, 0, 0, 0};
#pragma unroll 5
        for (int i = 0; i < 25; ++i) {
            uint4 c = *(const uint4*)&blkcnt_e[(size_t)(g * 25 + i) * EW + w4 * 4];
            s.x += c.x; s.y += c.y; s.z += c.z; s.w += c.w;
        }
        *(uint4*)&gse[g * EW + w4 * 4] = s;
        return;
    }
    const int vid = (bid - 25) * 256 + threadIdx.x;   // vertex: 25 groups x 1250 uint4
    if (vid >= 25 * (VWR / 4)) return;
    const int g = vid / (VWR / 4), w4 = vid % (VWR / 4);
    const int r = g / 5, cg = g % 5;
    uint4 s = {0, 0, 0, 0};
#pragma unroll 5
    for (int i = 0; i < 25; ++i) {
        uint4 c = *(const uint4*)&blkcnt_v[(size_t)(r * NCHUNK + cg * 25 + i) * VWR + w4 * 4];
        s.x += c.x; s.y += c.y; s.z += c.z; s.w += c.w;
    }
    *(uint4*)&gsv[g * VWR + w4 * 4] = s;
}

// ---- p2o: cross-group exclusive scan + bin offsets (off/end) in one kernel ----
__global__ __launch_bounds__(256) void k_p2o(unsigned int* __restrict__ gse,
                                             unsigned int* __restrict__ gsv,
                                             int* __restrict__ off_e,
                                             int* __restrict__ end_e,
                                             int* __restrict__ off_v,
                                             int* __restrict__ end_v,
                                             int* __restrict__ totals) {
    __shared__ int s[256];
    __shared__ int base;
    const int bid = blockIdx.x, t = threadIdx.x;

    unsigned run = 0;
    int t0 = 0, t1 = 0, t2 = 0, t3 = 0;
    int binbase = -1;
    int* off; int* end; int* total;

    if (bid < 20) {                       // edge: word w = 4 bins
        const int w = bid * 256 + t;
#pragma unroll
        for (int g = 0; g < 5; ++g) {
            unsigned c = gse[g * EW + w];
            gse[g * EW + w] = run;
            run += c;
        }
        t0 = run & 255; t1 = (run >> 8) & 255; t2 = (run >> 16) & 255; t3 = run >> 24;
        binbase = 4 * w;
        off = off_e; end = end_e; total = &totals[0];
    } else {                              // vertex: 5 ranges x 5000 words
        const int id = (bid - 20) * 256 + t;
        if (id < NRANGE * VWR) {
            const int r = id / VWR, w = id % VWR;
#pragma unroll
            for (int g = r * 5; g < r * 5 + 5; ++g) {
                unsigned c = gsv[g * VWR + w];
                gsv[g * VWR + w] = run;
                run += c;
            }
            t0 = run & 255; t1 = (run >> 8) & 255; t2 = (run >> 16) & 255; t3 = run >> 24;
            binbase = r * VBIN_R + 4 * w;
        }
        off = off_v; end = end_v; total = &totals[1];
    }

    const int mysum = t0 + t1 + t2 + t3;
    s[t] = mysum;
    __syncthreads();
    for (int d = 1; d < 256; d <<= 1) {
        int x = (t >= d) ? s[t - d] : 0;
        __syncthreads();
        s[t] += x;
        __syncthreads();
    }
    if (t == 0) base = atomicAdd(total, s[255]);
    __syncthreads();
    if (binbase >= 0) {
        int b = base + s[t] - mysum;
        off[binbase]     = b;           end[binbase]     = b + t0;  b += t0;
        off[binbase + 1] = b;           end[binbase + 1] = b + t1;  b += t1;
        off[binbase + 2] = b;           end[binbase + 2] = b + t2;  b += t2;
        off[binbase + 3] = b;           end[binbase + 3] = b + t3;
    }
}

// ---- scan p3: per-chunk exclusive prefixes, uint4-vectorized ----
__global__ __launch_bounds__(256) void k_scan_p3(unsigned int* __restrict__ blkcnt_e,
                                                 unsigned int* __restrict__ blkcnt_v,
                                                 const unsigned int* __restrict__ gse,
                                                 const unsigned int* __restrict__ gsv) {
    const int bid = blockIdx.x;
    if (bid < 25) {
        const int gid = bid * 256 + threadIdx.x;      // 6400
        const int g = gid / 1280, w4 = gid % 1280;
        uint4 run = *(const uint4*)&gse[g * EW + w4 * 4];
#pragma unroll 5
        for (int i = 0; i < 25; ++i) {
            unsigned int* p = (unsigned int*)&blkcnt_e[(size_t)(g * 25 + i) * EW + w4 * 4];
            uint4 c = *(uint4*)p;
            *(uint4*)p = run;
            run.x += c.x; run.y += c.y; run.z += c.z; run.w += c.w;
        }
        return;
    }
    const int vid = (bid - 25) * 256 + threadIdx.x;
    if (vid >= 25 * (VWR / 4)) return;
    const int g = vid / (VWR / 4), w4 = vid % (VWR / 4);
    const int r = g / 5, cg = g % 5;
    uint4 run = *(const uint4*)&gsv[g * VWR + w4 * 4];
#pragma unroll 5
    for (int i = 0; i < 25; ++i) {
        unsigned int* p = (unsigned int*)&blkcnt_v[(size_t)(r * NCHUNK + cg * 25 + i) * VWR + w4 * 4];
        uint4 c = *(uint4*)p;
        *(uint4*)p = run;
        run.x += c.x; run.y += c.y; run.z += c.z; run.w += c.w;
    }
}

// ------- atomic-free scatter -------
__global__ __launch_bounds__(256) void k_scatter(const int* __restrict__ vertex,
                                                 const int* __restrict__ edges,
                                                 const unsigned char* __restrict__ lrank_e,
                                                 const unsigned char* __restrict__ lrank_v5,
                                                 const unsigned int* __restrict__ blkcnt_e,
                                                 const unsigned int* __restrict__ blkcnt_v,
                                                 const int* __restrict__ off_e,
                                                 const int* __restrict__ off_v,
                                                 int* __restrict__ vlist_e,
                                                 int* __restrict__ elist_v) {
    const int m = blockIdx.x * 256 + threadIdx.x;
    const int e = edges[m];
    const int v = vertex[m];
    const int c = m / ECHUNK;
    const unsigned pe = blkcnt_e[(size_t)c * EW + (e >> 2)];
    const int er = (int)((pe >> ((unsigned)(e & 3) * 8u)) & 0xffu) + (int)lrank_e[m];
    const int r = v / VBIN_R, loc = v - r * VBIN_R;
    const unsigned pv = blkcnt_v[(size_t)(r * NCHUNK + c) * VWR + (loc >> 2)];
    const int vr = (int)((pv >> ((unsigned)(loc & 3) * 8u)) & 0xffu)
                 + (int)lrank_v5[(size_t)r * N_PAIRS + m];
    vlist_e[off_e[e] + er] = v;
    elist_v[off_v[v] + vr] = e;
}

// --------- per-edge: 16 lanes x 16B gathers, two rows per iteration ---------
__global__ __launch_bounds__(256) void k_edge(const short* __restrict__ X0h,
                                              const int* __restrict__ off_e,
                                              const int* __restrict__ end_e,
                                              const int* __restrict__ vlist,
                                              const float* __restrict__ att,
                                              short* __restrict__ Xeh,
                                              float* __restrict__ alpha_le) {
    const int t = threadIdx.x;
    const int slot = t >> 5, lane = t & 31;
    const int half = lane >> 4, cl = lane & 15;    // channels [cl*8, cl*8+8)
    const int e = blockIdx.x * 8 + slot;
    const int s = off_e[e], en = end_e[e];
    const int deg = en - s;
    const short* __restrict__ xb = X0h + cl * 8;

    float va[8] = {0.f, 0.f, 0.f, 0.f, 0.f, 0.f, 0.f, 0.f};
    for (int c0 = 0; c0 < deg; c0 += 32) {
        const int cn = min(32, deg - c0);
        int vl = (lane < cn) ? (vlist[s + c0 + lane] << 7) : 0;   // pre-scaled
#pragma unroll 4
        for (int j = 0; j < cn; j += 2) {
            const int jj = j + half;
            const int vo = __shfl(vl, jj, 32);
            if (jj < cn) {
                uint4 xq = *(const uint4*)(xb + vo);
                va[0] += bflo(xq.x); va[1] += bfhi(xq.x);
                va[2] += bflo(xq.y); va[3] += bfhi(xq.y);
                va[4] += bflo(xq.z); va[5] += bfhi(xq.z);
                va[6] += bflo(xq.w); va[7] += bfhi(xq.w);
            }
        }
    }
#pragma unroll
    for (int i = 0; i < 8; ++i) va[i] += __shfl_xor(va[i], 16);

    const float invd = 1.0f / fmaxf((float)deg, 1.0f);
    bf16x8 xh;
    float xe[8];
#pragma unroll
    for (int i = 0; i < 8; ++i) { xe[i] = va[i] * invd; xh[i] = f2bf(xe[i]); }
    if (half == 0) *(bf16x8*)&Xeh[(size_t)e * CH + cl * 8] = xh;

    const float4 a0 = *(const float4*)&att[cl * 8];
    const float4 a1 = *(const float4*)&att[cl * 8 + 4];
    float p = xe[0] * a0.x + xe[1] * a0.y + xe[2] * a0.z + xe[3] * a0.w
            + xe[4] * a1.x + xe[5] * a1.y + xe[6] * a1.z + xe[7] * a1.w;
    p += __shfl_xor(p, 1);
    p += __shfl_xor(p, 2);
    if (half == 0 && (cl & 3) == 0) {
        alpha_le[e * HEADS + (cl >> 2)] = (p > 0.f) ? p : 0.01f * p;
    }
}

// --------- per-vertex: 16 lanes/vertex, 2 vertices/slot; exp cached in LDS ---------
__global__ __launch_bounds__(256) void k_vertex(const short* __restrict__ X0h,
                                                const short* __restrict__ Xeh,
                                                const float* __restrict__ alpha_le,
                                                const int* __restrict__ off_v,
                                                const int* __restrict__ end_v,
                                                const int* __restrict__ elist,
                                                float* __restrict__ out) {
    const int t = threadIdx.x;
    const int slot = t >> 5, lane = t & 31;
    const int grp = lane >> 4, cl = lane & 15, h = cl >> 2;
    const int v = blockIdx.x * 16 + slot * 2 + grp;   // 6250*16 = 100000
    const int s = off_v[v], en = end_v[v];
    const int deg = en - s;

    __shared__ int   se[8][2][MAXDV];        // pre-scaled (e*CH)
    __shared__ float sa[8][2][MAXDV * HEADS];

    const short* __restrict__ xb = Xeh + cl * 8;

    float va[8] = {0.f, 0.f, 0.f, 0.f, 0.f, 0.f, 0.f, 0.f};
    if (deg <= MAXDV) {
        for (int j = cl; j < deg; j += 16) {
            const int e = elist[s + j];
            se[slot][grp][j] = e << 7;
            *(float4*)&sa[slot][grp][j << 2] = *(const float4*)&alpha_le[e * HEADS];
        }
        float mx = -INFINITY;
        for (int j = 0; j < deg; ++j) mx = fmaxf(mx, sa[slot][grp][(j << 2) + h]);
        float ssum = 0.f;
        for (int j = 0; j < deg; ++j) {
            const float p = __expf(sa[slot][grp][(j << 2) + h] - mx);
            sa[slot][grp][(j << 2) + h] = p;
            ssum += p;
        }
        const float inv = 1.0f / (ssum + 1e-8f);
        for (int j = 0; j < deg; ++j) {
            const float w = sa[slot][grp][(j << 2) + h] * inv;
            uint4 xq = *(const uint4*)(xb + se[slot][grp][j]);
            va[0] += w * bflo(xq.x); va[1] += w * bfhi(xq.x);
            va[2] += w * bflo(xq.y); va[3] += w * bfhi(xq.y);
            va[4] += w * bflo(xq.z); va[5] += w * bfhi(xq.z);
            va[6] += w * bflo(xq.w); va[7] += w * bfhi(xq.w);
        }
    } else {
        // global fallback (never taken for Poisson(6.4); correctness only)
        float mx = -INFINITY;
        for (int j = 0; j < deg; ++j) mx = fmaxf(mx, alpha_le[elist[s + j] * HEADS + h]);
        float ssum = 0.f;
        for (int j = 0; j < deg; ++j) ssum += __expf(alpha_le[elist[s + j] * HEADS + h] - mx);
        const float inv = 1.0f / (ssum + 1e-8f);
        for (int j = 0; j < deg; ++j) {
            const int e = elist[s + j];
            const float w = __expf(alpha_le[e * HEADS + h] - mx) * inv;
            uint4 xq = *(const uint4*)(xb + (e << 7));
            va[0] += w * bflo(xq.x); va[1] += w * bfhi(xq.x);
            va[2] += w * bflo(xq.y); va[3] += w * bfhi(xq.y);
            va[4] += w * bflo(xq.z); va[5] += w * bfhi(xq.z);
            va[6] += w * bflo(xq.w); va[7] += w * bfhi(xq.w);
        }
    }

    const uint4 rq = *(const uint4*)&X0h[(size_t)v * CH + cl * 8];
    float4 o0, o1;
    o0.x = va[0] + bflo(rq.x); o0.y = va[1] + bfhi(rq.x);
    o0.z = va[2] + bflo(rq.y); o0.w = va[3] + bfhi(rq.y);
    o1.x = va[4] + bflo(rq.z); o1.y = va[5] + bfhi(rq.z);
    o1.z = va[6] + bflo(rq.w); o1.w = va[7] + bfhi(rq.w);
    *(float4*)&out[(size_t)v * CH + cl * 8]     = o0;
    *(float4*)&out[(size_t)v * CH + cl * 8 + 4] = o1;
}

extern "C" void kernel_launch(void* const* d_in, const int* in_sizes, int n_in,
                              void* d_out, int out_size, void* d_ws, size_t ws_size,
                              hipStream_t stream) {
    const float* X      = (const float*)d_in[0];
    const float* W      = (const float*)d_in[1];
    const float* att    = (const float*)d_in[2];
    const int*   vertex = (const int*)d_in[3];
    const int*   edges  = (const int*)d_in[4];
    float* out = (float*)d_out;

    char* ws = (char*)d_ws;
    short* X0h      = (short*)(ws + OFF_X0H);
    short* Xeh      = (short*)(ws + OFF_XEH);
    unsigned char* lrank_e  = (unsigned char*)(ws + OFF_LRE);
    unsigned char* lrank_v5 = (unsigned char*)(ws + OFF_LRV5);
    unsigned int*  blkcnt_e = (unsigned int*)(ws + OFF_BLKE);
    unsigned int*  blkcnt_v = (unsigned int*)(ws + OFF_BLKV);
    unsigned int*  gse      = (unsigned int*)(ws + OFF_GSE);
    unsigned int*  gsv      = (unsigned int*)(ws + OFF_GSV);
    short* Wt       = (short*)(ws + OFF_WT);
    float* alpha_le = (float*)(ws + OFF_ALPHA);
    int* off_e   = (int*)(ws + OFF_OFFE);
    int* end_e   = (int*)(ws + OFF_ENDE);
    int* off_v   = (int*)(ws + OFF_OFFV);
    int* end_v   = (int*)(ws + OFF_ENDV);
    int* vlist_e = (int*)(ws + OFF_PIDXE);
    int* elist_v = (int*)(ws + OFF_PIDXV);
    int* totals  = (int*)(ws + OFF_TOT);

    hipMemsetAsync(ws + OFF_TOT, 0, ZERO_BYTES, stream);

    k_wprep<<<64, 256, 0, stream>>>(W, Wt);
    k_phase1<<<NG_GEMM + NRANGE * NCHUNK + NCHUNK, 256, 0, stream>>>(
        X, Wt, X0h, vertex, edges, lrank_e, lrank_v5, blkcnt_e, blkcnt_v);
    k_scan_p1<<<25 + 123, 256, 0, stream>>>(blkcnt_e, blkcnt_v, gse, gsv);
    k_p2o<<<20 + 98, 256, 0, stream>>>(gse, gsv, off_e, end_e, off_v, end_v, totals);
    k_scan_p3<<<25 + 123, 256, 0, stream>>>(blkcnt_e, blkcnt_v, gse, gsv);
    k_scatter<<<N_PAIRS / 256, 256, 0, stream>>>(vertex, edges, lrank_e, lrank_v5,
                                                 blkcnt_e, blkcnt_v, off_e, off_v,
                                                 vlist_e, elist_v);
    k_edge<<<N_EDGES / 8, 256, 0, stream>>>(X0h, off_e, end_e, vlist_e, att, Xeh, alpha_le);
    k_vertex<<<N_NODES / 16, 256, 0, stream>>>(X0h, Xeh, alpha_le, off_v, end_v, elist_v, out);
}

// Round 18
// 147.043 us; speedup vs baseline: 1.0136x; 1.0136x over previous
//
#include <hip/hip_runtime.h>
#include <hip/hip_bf16.h>

#define N_NODES 100000
#define N_EDGES 20000
#define N_PAIRS 640000
#define CH 128      // HEADS * OUT_CH
#define HEADS 4
#define MAXDV 32    // per-vertex fast-path capacity (Poisson(6.4): max ~25)

#define NG_GEMM 1563            // (N_NODES+63)/64
#define NCHUNK 125              // pair chunks (both sides)
#define ECHUNK 5120             // pairs per chunk
#define EW 5120                 // edge hist words (20480 bins @ 4x8b) = 20.48KB
#define VWR 5000                // vertex hist words per range (20000 bins @ 4x8b)
#define NRANGE 5
#define VBIN_R 20000

// ---- workspace layout (bytes), all 16B-aligned ----
#define OFF_X0H   0UL           // 25,600,000
#define OFF_XEH   25600000UL    //  5,120,000
#define OFF_LRE   30720000UL    //    640,000 u8 (edge local rank)
#define OFF_LRV5  31360000UL    //  5*640,000 u8 (vertex local rank, per range)
#define OFF_BLKE  34560000UL    // 125*5120 u32 =  2,560,000
#define OFF_BLKV  37120000UL    // 625*5000 u32 = 12,500,000
#define OFF_GSE   49620000UL    //   5*5120 u32 =    102,400
#define OFF_GSV   49722400UL    //  25*5000 u32 =    500,000
#define OFF_WT    50222400UL    //     32,768
#define OFF_ALPHA 50255168UL    //    320,000
#define OFF_OFFE  50575168UL    //     81,920 (20480 i32)
#define OFF_ENDE  50657088UL    //     81,920
#define OFF_OFFV  50739008UL    //    400,000
#define OFF_ENDV  51139008UL    //    400,000
#define OFF_PIDXE 51539008UL    //  2,560,000 (VERTEX ids, edge-grouped)
#define OFF_PIDXV 54099008UL    //  2,560,000 (EDGE ids, vertex-grouped)
#define OFF_TOT   56659008UL    //          8  } only zero region
#define ZERO_BYTES 8UL

typedef __attribute__((ext_vector_type(8))) short bf16x8;
typedef __attribute__((ext_vector_type(4))) float f32x4;

__device__ inline short f2bf(float f) {
    __hip_bfloat16 h = __float2bfloat16(f);   // RNE
    return reinterpret_cast<short&>(h);
}
__device__ inline float bflo(unsigned w) { return __uint_as_float(w << 16); }
__device__ inline float bfhi(unsigned w) { return __uint_as_float(w & 0xffff0000u); }

// ---- W prep: Wt[n][k] = bf16(W[k][n]) ----
__global__ __launch_bounds__(256) void k_wprep(const float* __restrict__ W,
                                               short* __restrict__ Wt) {
    const int idx = blockIdx.x * 256 + threadIdx.x;   // 64 * 256
    const int n = idx >> 7, k = idx & 127;
    Wt[n * CH + k] = f2bf(W[k * CH + n]);
}

// ---- gemm body: depth-2 software pipeline (R16 reference) ----
__device__ inline void gemm_body(int gb, const float* __restrict__ X,
                                 const short* __restrict__ Wt,
                                 short* __restrict__ X0h) {
    const int t = threadIdx.x;
    const int wave = t >> 6, lane = t & 63;
    const int r0 = gb * 64 + (wave >> 1) * 32;
    const int c0 = (wave & 1) * 64;
    const int lrow = lane & 15, lk8 = (lane >> 4) * 8;
    const int row0 = min(r0 + lrow, N_NODES - 1);
    const int row1 = min(r0 + 16 + lrow, N_NODES - 1);
    const float* px0 = &X[(size_t)row0 * CH + lk8];
    const float* px1 = &X[(size_t)row1 * CH + lk8];
    const short* pw0 = &Wt[(size_t)(c0 + lrow) * CH + lk8];

    f32x4 acc[2][4] = {};

    float4 xa[2][2]; bf16x8 bb[4];
    xa[0][0] = *(const float4*)(px0); xa[0][1] = *(const float4*)(px0 + 4);
    xa[1][0] = *(const float4*)(px1); xa[1][1] = *(const float4*)(px1 + 4);
#pragma unroll
    for (int n = 0; n < 4; ++n) bb[n] = *(const bf16x8*)(pw0 + n * 16 * CH);

#pragma unroll
    for (int kk = 0; kk < 4; ++kk) {
        float4 xn[2][2]; bf16x8 bn[4];
        if (kk < 3) {
            const int ks = (kk + 1) * 32;
            xn[0][0] = *(const float4*)(px0 + ks); xn[0][1] = *(const float4*)(px0 + ks + 4);
            xn[1][0] = *(const float4*)(px1 + ks); xn[1][1] = *(const float4*)(px1 + ks + 4);
#pragma unroll
            for (int n = 0; n < 4; ++n) bn[n] = *(const bf16x8*)(pw0 + n * 16 * CH + ks);
        }
        bf16x8 a[2];
#pragma unroll
        for (int m = 0; m < 2; ++m) {
            a[m][0] = f2bf(xa[m][0].x); a[m][1] = f2bf(xa[m][0].y);
            a[m][2] = f2bf(xa[m][0].z); a[m][3] = f2bf(xa[m][0].w);
            a[m][4] = f2bf(xa[m][1].x); a[m][5] = f2bf(xa[m][1].y);
            a[m][6] = f2bf(xa[m][1].z); a[m][7] = f2bf(xa[m][1].w);
        }
#pragma unroll
        for (int m = 0; m < 2; ++m)
#pragma unroll
            for (int n = 0; n < 4; ++n)
                acc[m][n] = __builtin_amdgcn_mfma_f32_16x16x32_bf16(a[m], bb[n], acc[m][n], 0, 0, 0);
        if (kk < 3) {
#pragma unroll
            for (int m = 0; m < 2; ++m) { xa[m][0] = xn[m][0]; xa[m][1] = xn[m][1]; }
#pragma unroll
            for (int n = 0; n < 4; ++n) bb[n] = bn[n];
        }
    }

    // C/D layout: col = lane&15, row = (lane>>4)*4 + reg   [m89-verified]
#pragma unroll
    for (int m = 0; m < 2; ++m) {
#pragma unroll
        for (int reg = 0; reg < 4; ++reg) {
            const int row = r0 + m * 16 + (lane >> 4) * 4 + reg;
            if (row < N_NODES) {
#pragma unroll
                for (int n = 0; n < 4; ++n)
                    X0h[(size_t)row * CH + c0 + n * 16 + (lane & 15)] = f2bf(acc[m][n][reg]);
            }
        }
    }
}

// ====== FUSED phase 1: vcount(625) | ecount(125) | gemm(1563); 20KB LDS ======
__global__ __launch_bounds__(256) void k_phase1(const float* __restrict__ X,
                                                const short* __restrict__ Wt,
                                                short* __restrict__ X0h,
                                                const int* __restrict__ vertex,
                                                const int* __restrict__ edges,
                                                unsigned char* __restrict__ lrank_e,
                                                unsigned char* __restrict__ lrank_v5,
                                                unsigned int* __restrict__ blkcnt_e,
                                                unsigned int* __restrict__ blkcnt_v) {
    __shared__ unsigned int hist[EW];   // 20,480 B
    const int bid = blockIdx.x;
    const int t = threadIdx.x;

    if (bid < NRANGE * NCHUNK) {
        // ---- vcount: range r, chunk c (5,120 pairs; 20 iters -> short block) ----
        const int r = bid % NRANGE, c = bid / NRANGE;
        for (int i = t; i < VWR; i += 256) hist[i] = 0;
        __syncthreads();
        const int base = c * ECHUNK;
        const int vmin = r * VBIN_R;
        unsigned char* __restrict__ lr = lrank_v5 + (size_t)r * N_PAIRS;
#pragma unroll
        for (int it = 0; it < 20; ++it) {
            const int m = base + it * 256 + t;
            const int loc = vertex[m] - vmin;
            if ((unsigned)loc < (unsigned)VBIN_R) {
                const unsigned sh = (unsigned)(loc & 3) * 8u;
                unsigned old = atomicAdd(&hist[loc >> 2], 1u << sh);
                lr[m] = (unsigned char)((old >> sh) & 0xffu);
            }
        }
        __syncthreads();
        unsigned int* dst = &blkcnt_v[(size_t)(r * NCHUNK + c) * VWR];
        for (int w = t; w < VWR; w += 256) dst[w] = hist[w];
        return;
    }
    if (bid < NRANGE * NCHUNK + NCHUNK) {
        // ---- ecount: chunk c ----
        const int c = bid - NRANGE * NCHUNK;
        for (int i = t; i < EW; i += 256) hist[i] = 0;
        __syncthreads();
        const int base = c * ECHUNK;
#pragma unroll
        for (int it = 0; it < 20; ++it) {
            const int m = base + it * 256 + t;
            const int e = edges[m];
            const unsigned sh = (unsigned)(e & 3) * 8u;
            unsigned old = atomicAdd(&hist[e >> 2], 1u << sh);
            lrank_e[m] = (unsigned char)((old >> sh) & 0xffu);
        }
        __syncthreads();
        unsigned int* dst = &blkcnt_e[(size_t)c * EW];
        for (int w = t; w < EW; w += 256) dst[w] = hist[w];
        return;
    }
    gemm_body(bid - (NRANGE * NCHUNK + NCHUNK), X, Wt, X0h);
}

// ---- scan p1: group partial sums, uint4-vectorized ----
__global__ __launch_bounds__(256) void k_scan_p1(const unsigned int* __restrict__ blkcnt_e,
                                                 const unsigned int* __restrict__ blkcnt_v,
                                                 unsigned int* __restrict__ gse,
                                                 unsigned int* __restrict__ gsv) {
    const int bid = blockIdx.x;
    if (bid < 25) {                                   // edge: 5 groups x 1280 uint4
        const int gid = bid * 256 + threadIdx.x;      // 6400
        const int g = gid / 1280, w4 = gid % 1280;
        uint4 s = {0, 0, 0, 0};
#pragma unroll 5
        for (int i = 0; i < 25; ++i) {
            uint4 c = *(const uint4*)&blkcnt_e[(size_t)(g * 25 + i) * EW + w4 * 4];
            s.x += c.x; s.y += c.y; s.z += c.z; s.w += c.w;
        }
        *(uint4*)&gse[g * EW + w4 * 4] = s;
        return;
    }
    const int vid = (bid - 25) * 256 + threadIdx.x;   // vertex: 25 groups x 1250 uint4
    if (vid >= 25 * (VWR / 4)) return;
    const int g = vid / (VWR / 4), w4 = vid % (VWR / 4);
    const int r = g / 5, cg = g % 5;
    uint4 s = {0, 0, 0, 0};
#pragma unroll 5
    for (int i = 0; i < 25; ++i) {
        uint4 c = *(const uint4*)&blkcnt_v[(size_t)(r * NCHUNK + cg * 25 + i) * VWR + w4 * 4];
        s.x += c.x; s.y += c.y; s.z += c.z; s.w += c.w;
    }
    *(uint4*)&gsv[g * VWR + w4 * 4] = s;
}

// ---- p2o: cross-group exclusive scan + bin offsets (off/end) in one kernel ----
__global__ __launch_bounds__(256) void k_p2o(unsigned int* __restrict__ gse,
                                             unsigned int* __restrict__ gsv,
                                             int* __restrict__ off_e,
                                             int* __restrict__ end_e,
                                             int* __restrict__ off_v,
                                             int* __restrict__ end_v,
                                             int* __restrict__ totals) {
    __shared__ int s[256];
    __shared__ int base;
    const int bid = blockIdx.x, t = threadIdx.x;

    unsigned run = 0;
    int t0 = 0, t1 = 0, t2 = 0, t3 = 0;
    int binbase = -1;
    int* off; int* end; int* total;

    if (bid < 20) {                       // edge: word w = 4 bins
        const int w = bid * 256 + t;
#pragma unroll
        for (int g = 0; g < 5; ++g) {
            unsigned c = gse[g * EW + w];
            gse[g * EW + w] = run;
            run += c;
        }
        t0 = run & 255; t1 = (run >> 8) & 255; t2 = (run >> 16) & 255; t3 = run >> 24;
        binbase = 4 * w;
        off = off_e; end = end_e; total = &totals[0];
    } else {                              // vertex: 5 ranges x 5000 words
        const int id = (bid - 20) * 256 + t;
        if (id < NRANGE * VWR) {
            const int r = id / VWR, w = id % VWR;
#pragma unroll
            for (int g = r * 5; g < r * 5 + 5; ++g) {
                unsigned c = gsv[g * VWR + w];
                gsv[g * VWR + w] = run;
                run += c;
            }
            t0 = run & 255; t1 = (run >> 8) & 255; t2 = (run >> 16) & 255; t3 = run >> 24;
            binbase = r * VBIN_R + 4 * w;
        }
        off = off_v; end = end_v; total = &totals[1];
    }

    const int mysum = t0 + t1 + t2 + t3;
    s[t] = mysum;
    __syncthreads();
    for (int d = 1; d < 256; d <<= 1) {
        int x = (t >= d) ? s[t - d] : 0;
        __syncthreads();
        s[t] += x;
        __syncthreads();
    }
    if (t == 0) base = atomicAdd(total, s[255]);
    __syncthreads();
    if (binbase >= 0) {
        int b = base + s[t] - mysum;
        off[binbase]     = b;           end[binbase]     = b + t0;  b += t0;
        off[binbase + 1] = b;           end[binbase + 1] = b + t1;  b += t1;
        off[binbase + 2] = b;           end[binbase + 2] = b + t2;  b += t2;
        off[binbase + 3] = b;           end[binbase + 3] = b + t3;
    }
}

// ---- scan p3: per-chunk exclusive prefixes, uint4-vectorized ----
__global__ __launch_bounds__(256) void k_scan_p3(unsigned int* __restrict__ blkcnt_e,
                                                 unsigned int* __restrict__ blkcnt_v,
                                                 const unsigned int* __restrict__ gse,
                                                 const unsigned int* __restrict__ gsv) {
    const int bid = blockIdx.x;
    if (bid < 25) {
        const int gid = bid * 256 + threadIdx.x;      // 6400
        const int g = gid / 1280, w4 = gid % 1280;
        uint4 run = *(const uint4*)&gse[g * EW + w4 * 4];
#pragma unroll 5
        for (int i = 0; i < 25; ++i) {
            unsigned int* p = (unsigned int*)&blkcnt_e[(size_t)(g * 25 + i) * EW + w4 * 4];
            uint4 c = *(uint4*)p;
            *(uint4*)p = run;
            run.x += c.x; run.y += c.y; run.z += c.z; run.w += c.w;
        }
        return;
    }
    const int vid = (bid - 25) * 256 + threadIdx.x;
    if (vid >= 25 * (VWR / 4)) return;
    const int g = vid / (VWR / 4), w4 = vid % (VWR / 4);
    const int r = g / 5, cg = g % 5;
    uint4 run = *(const uint4*)&gsv[g * VWR + w4 * 4];
#pragma unroll 5
    for (int i = 0; i < 25; ++i) {
        unsigned int* p = (unsigned int*)&blkcnt_v[(size_t)(r * NCHUNK + cg * 25 + i) * VWR + w4 * 4];
        uint4 c = *(uint4*)p;
        *(uint4*)p = run;
        run.x += c.x; run.y += c.y; run.z += c.z; run.w += c.w;
    }
}

// ------- atomic-free scatter -------
__global__ __launch_bounds__(256) void k_scatter(const int* __restrict__ vertex,
                                                 const int* __restrict__ edges,
                                                 const unsigned char* __restrict__ lrank_e,
                                                 const unsigned char* __restrict__ lrank_v5,
                                                 const unsigned int* __restrict__ blkcnt_e,
                                                 const unsigned int* __restrict__ blkcnt_v,
                                                 const int* __restrict__ off_e,
                                                 const int* __restrict__ off_v,
                                                 int* __restrict__ vlist_e,
                                                 int* __restrict__ elist_v) {
    const int m = blockIdx.x * 256 + threadIdx.x;
    const int e = edges[m];
    const int v = vertex[m];
    const int c = m / ECHUNK;
    const unsigned pe = blkcnt_e[(size_t)c * EW + (e >> 2)];
    const int er = (int)((pe >> ((unsigned)(e & 3) * 8u)) & 0xffu) + (int)lrank_e[m];
    const int r = v / VBIN_R, loc = v - r * VBIN_R;
    const unsigned pv = blkcnt_v[(size_t)(r * NCHUNK + c) * VWR + (loc >> 2)];
    const int vr = (int)((pv >> ((unsigned)(loc & 3) * 8u)) & 0xffu)
                 + (int)lrank_v5[(size_t)r * N_PAIRS + m];
    vlist_e[off_e[e] + er] = v;
    elist_v[off_v[v] + vr] = e;
}

// --------- per-edge: 16 lanes/edge, 2 edges/slot; full row per iteration ---------
__global__ __launch_bounds__(256) void k_edge(const short* __restrict__ X0h,
                                              const int* __restrict__ off_e,
                                              const int* __restrict__ end_e,
                                              const int* __restrict__ vlist,
                                              const float* __restrict__ att,
                                              short* __restrict__ Xeh,
                                              float* __restrict__ alpha_le) {
    const int t = threadIdx.x;
    const int slot = t >> 5, lane = t & 31;
    const int grp = lane >> 4, cl = lane & 15;     // channels [cl*8, cl*8+8)
    const int e = blockIdx.x * 16 + slot * 2 + grp;  // grid 1250 * 16 = 20000
    const int s = off_e[e], en = end_e[e];
    const int deg = en - s;
    const short* __restrict__ xb = X0h + cl * 8;

    float va[8] = {0.f, 0.f, 0.f, 0.f, 0.f, 0.f, 0.f, 0.f};
    for (int c0 = 0; c0 < deg; c0 += 16) {
        const int cn = min(16, deg - c0);
        int vl = (cl < cn) ? (vlist[s + c0 + cl] << 7) : 0;   // pre-scaled
#pragma unroll 4
        for (int j = 0; j < cn; ++j) {
            const int vo = __shfl(vl, grp * 16 + j, 32);      // within my 16-group
            uint4 xq = *(const uint4*)(xb + vo);
            va[0] += bflo(xq.x); va[1] += bfhi(xq.x);
            va[2] += bflo(xq.y); va[3] += bfhi(xq.y);
            va[4] += bflo(xq.z); va[5] += bfhi(xq.z);
            va[6] += bflo(xq.w); va[7] += bfhi(xq.w);
        }
    }

    const float invd = 1.0f / fmaxf((float)deg, 1.0f);
    bf16x8 xh;
    float xe[8];
#pragma unroll
    for (int i = 0; i < 8; ++i) { xe[i] = va[i] * invd; xh[i] = f2bf(xe[i]); }
    *(bf16x8*)&Xeh[(size_t)e * CH + cl * 8] = xh;

    const float4 a0 = *(const float4*)&att[cl * 8];
    const float4 a1 = *(const float4*)&att[cl * 8 + 4];
    float p = xe[0] * a0.x + xe[1] * a0.y + xe[2] * a0.z + xe[3] * a0.w
            + xe[4] * a1.x + xe[5] * a1.y + xe[6] * a1.z + xe[7] * a1.w;
    p += __shfl_xor(p, 1);
    p += __shfl_xor(p, 2);     // sum over the 4 lanes of this head group
    if ((cl & 3) == 0) {
        alpha_le[e * HEADS + (cl >> 2)] = (p > 0.f) ? p : 0.01f * p;
    }
}

// --------- per-vertex: 16 lanes/vertex, 2 vertices/slot; exp cached in LDS ---------
__global__ __launch_bounds__(256) void k_vertex(const short* __restrict__ X0h,
                                                const short* __restrict__ Xeh,
                                                const float* __restrict__ alpha_le,
                                                const int* __restrict__ off_v,
                                                const int* __restrict__ end_v,
                                                const int* __restrict__ elist,
                                                float* __restrict__ out) {
    const int t = threadIdx.x;
    const int slot = t >> 5, lane = t & 31;
    const int grp = lane >> 4, cl = lane & 15, h = cl >> 2;
    const int v = blockIdx.x * 16 + slot * 2 + grp;   // 6250*16 = 100000
    const int s = off_v[v], en = end_v[v];
    const int deg = en - s;

    __shared__ int   se[8][2][MAXDV];        // pre-scaled (e*CH)
    __shared__ float sa[8][2][MAXDV * HEADS];

    const short* __restrict__ xb = Xeh + cl * 8;

    float va[8] = {0.f, 0.f, 0.f, 0.f, 0.f, 0.f, 0.f, 0.f};
    if (deg <= MAXDV) {
        for (int j = cl; j < deg; j += 16) {
            const int e = elist[s + j];
            se[slot][grp][j] = e << 7;
            *(float4*)&sa[slot][grp][j << 2] = *(const float4*)&alpha_le[e * HEADS];
        }
        float mx = -INFINITY;
        for (int j = 0; j < deg; ++j) mx = fmaxf(mx, sa[slot][grp][(j << 2) + h]);
        float ssum = 0.f;
        for (int j = 0; j < deg; ++j) {
            const float p = __expf(sa[slot][grp][(j << 2) + h] - mx);
            sa[slot][grp][(j << 2) + h] = p;
            ssum += p;
        }
        const float inv = 1.0f / (ssum + 1e-8f);
        for (int j = 0; j < deg; ++j) {
            const float w = sa[slot][grp][(j << 2) + h] * inv;
            uint4 xq = *(const uint4*)(xb + se[slot][grp][j]);
            va[0] += w * bflo(xq.x); va[1] += w * bfhi(xq.x);
            va[2] += w * bflo(xq.y); va[3] += w * bfhi(xq.y);
            va[4] += w * bflo(xq.z); va[5] += w * bfhi(xq.z);
            va[6] += w * bflo(xq.w); va[7] += w * bfhi(xq.w);
        }
    } else {
        // global fallback (never taken for Poisson(6.4); correctness only)
        float mx = -INFINITY;
        for (int j = 0; j < deg; ++j) mx = fmaxf(mx, alpha_le[elist[s + j] * HEADS + h]);
        float ssum = 0.f;
        for (int j = 0; j < deg; ++j) ssum += __expf(alpha_le[elist[s + j] * HEADS + h] - mx);
        const float inv = 1.0f / (ssum + 1e-8f);
        for (int j = 0; j < deg; ++j) {
            const int e = elist[s + j];
            const float w = __expf(alpha_le[e * HEADS + h] - mx) * inv;
            uint4 xq = *(const uint4*)(xb + (e << 7));
            va[0] += w * bflo(xq.x); va[1] += w * bfhi(xq.x);
            va[2] += w * bflo(xq.y); va[3] += w * bfhi(xq.y);
            va[4] += w * bflo(xq.z); va[5] += w * bfhi(xq.z);
            va[6] += w * bflo(xq.w); va[7] += w * bfhi(xq.w);
        }
    }

    const uint4 rq = *(const uint4*)&X0h[(size_t)v * CH + cl * 8];
    float4 o0, o1;
    o0.x = va[0] + bflo(rq.x); o0.y = va[1] + bfhi(rq.x);
    o0.z = va[2] + bflo(rq.y); o0.w = va[3] + bfhi(rq.y);
    o1.x = va[4] + bflo(rq.z); o1.y = va[5] + bfhi(rq.z);
    o1.z = va[6] + bflo(rq.w); o1.w = va[7] + bfhi(rq.w);
    *(float4*)&out[(size_t)v * CH + cl * 8]     = o0;
    *(float4*)&out[(size_t)v * CH + cl * 8 + 4] = o1;
}

extern "C" void kernel_launch(void* const* d_in, const int* in_sizes, int n_in,
                              void* d_out, int out_size, void* d_ws, size_t ws_size,
                              hipStream_t stream) {
    const float* X      = (const float*)d_in[0];
    const float* W      = (const float*)d_in[1];
    const float* att    = (const float*)d_in[2];
    const int*   vertex = (const int*)d_in[3];
    const int*   edges  = (const int*)d_in[4];
    float* out = (float*)d_out;

    char* ws = (char*)d_ws;
    short* X0h      = (short*)(ws + OFF_X0H);
    short* Xeh      = (short*)(ws + OFF_XEH);
    unsigned char* lrank_e  = (unsigned char*)(ws + OFF_LRE);
    unsigned char* lrank_v5 = (unsigned char*)(ws + OFF_LRV5);
    unsigned int*  blkcnt_e = (unsigned int*)(ws + OFF_BLKE);
    unsigned int*  blkcnt_v = (unsigned int*)(ws + OFF_BLKV);
    unsigned int*  gse      = (unsigned int*)(ws + OFF_GSE);
    unsigned int*  gsv      = (unsigned int*)(ws + OFF_GSV);
    short* Wt       = (short*)(ws + OFF_WT);
    float* alpha_le = (float*)(ws + OFF_ALPHA);
    int* off_e   = (int*)(ws + OFF_OFFE);
    int* end_e   = (int*)(ws + OFF_ENDE);
    int* off_v   = (int*)(ws + OFF_OFFV);
    int* end_v   = (int*)(ws + OFF_ENDV);
    int* vlist_e = (int*)(ws + OFF_PIDXE);
    int* elist_v = (int*)(ws + OFF_PIDXV);
    int* totals  = (int*)(ws + OFF_TOT);

    hipMemsetAsync(ws + OFF_TOT, 0, ZERO_BYTES, stream);

    k_wprep<<<64, 256, 0, stream>>>(W, Wt);
    k_phase1<<<NRANGE * NCHUNK + NCHUNK + NG_GEMM, 256, 0, stream>>>(
        X, Wt, X0h, vertex, edges, lrank_e, lrank_v5, blkcnt_e, blkcnt_v);
    k_scan_p1<<<25 + 123, 256, 0, stream>>>(blkcnt_e, blkcnt_v, gse, gsv);
    k_p2o<<<20 + 98, 256, 0, stream>>>(gse, gsv, off_e, end_e, off_v, end_v, totals);
    k_scan_p3<<<25 + 123, 256, 0, stream>>>(blkcnt_e, blkcnt_v, gse, gsv);
    k_scatter<<<N_PAIRS / 256, 256, 0, stream>>>(vertex, edges, lrank_e, lrank_v5,
                                                 blkcnt_e, blkcnt_v, off_e, off_v,
                                                 vlist_e, elist_v);
    k_edge<<<N_EDGES / 16, 256, 0, stream>>>(X0h, off_e, end_e, vlist_e, att, Xeh, alpha_le);
    k_vertex<<<N_NODES / 16, 256, 0, stream>>>(X0h, Xeh, alpha_le, off_v, end_v, elist_v, out);
}

// Round 19
// 144.451 us; speedup vs baseline: 1.0318x; 1.0179x over previous
//
#include <hip/hip_runtime.h>
#include <hip/hip_bf16.h>

#define N_NODES 100000
#define N_EDGES 20000
#define N_PAIRS 640000
#define CH 128      // HEADS * OUT_CH
#define HEADS 4
#define MAXDV 32    // per-vertex fast-path capacity (Poisson(6.4): max ~25)

#define NG_GEMM 1563            // (N_NODES+63)/64
#define NCHUNK 125              // pair chunks (both sides)
#define ECHUNK 5120             // pairs per chunk
#define EW 5120                 // edge hist words (20480 bins @ 4x8b) = 20.48KB
#define VWR 5000                // vertex hist words per range (20000 bins @ 4x8b)
#define NRANGE 5
#define VBIN_R 20000

// ---- workspace layout (bytes), all 16B-aligned ----
#define OFF_X0H   0UL           // 25,600,000
#define OFF_XEH   25600000UL    //  5,120,000
#define OFF_LRE   30720000UL    //    640,000 u8 (edge local rank)
#define OFF_LRV5  31360000UL    //  5*640,000 u8 (vertex local rank, per range)
#define OFF_BLKE  34560000UL    // 125*5120 u32 =  2,560,000
#define OFF_BLKV  37120000UL    // 625*5000 u32 = 12,500,000
#define OFF_WT    50222400UL    //     32,768
#define OFF_ALPHA 50255168UL    //    320,000
#define OFF_OFFE  50575168UL    //     81,920 (20480 i32)
#define OFF_ENDE  50657088UL    //     81,920
#define OFF_OFFV  50739008UL    //    400,000
#define OFF_ENDV  51139008UL    //    400,000
#define OFF_PIDXE 51539008UL    //  2,560,000 (VERTEX ids, edge-grouped)
#define OFF_PIDXV 54099008UL    //  2,560,000 (EDGE ids, vertex-grouped)
#define OFF_TOT   56659008UL    //          8 (zeroed by k_wprep each call)

typedef __attribute__((ext_vector_type(8))) short bf16x8;
typedef __attribute__((ext_vector_type(4))) float f32x4;

__device__ inline short f2bf(float f) {
    __hip_bfloat16 h = __float2bfloat16(f);   // RNE
    return reinterpret_cast<short&>(h);
}
__device__ inline float bflo(unsigned w) { return __uint_as_float(w << 16); }
__device__ inline float bfhi(unsigned w) { return __uint_as_float(w & 0xffff0000u); }

// ---- W prep: Wt[n][k] = bf16(W[k][n]); also zeroes totals (replaces memset) ----
__global__ __launch_bounds__(256) void k_wprep(const float* __restrict__ W,
                                               short* __restrict__ Wt,
                                               int* __restrict__ totals) {
    if (blockIdx.x == 0 && threadIdx.x < 2) totals[threadIdx.x] = 0;
    const int idx = blockIdx.x * 256 + threadIdx.x;   // 64 * 256
    const int n = idx >> 7, k = idx & 127;
    Wt[n * CH + k] = f2bf(W[k * CH + n]);
}

// ---- gemm body: depth-2 software pipeline (R16 reference) ----
__device__ inline void gemm_body(int gb, const float* __restrict__ X,
                                 const short* __restrict__ Wt,
                                 short* __restrict__ X0h) {
    const int t = threadIdx.x;
    const int wave = t >> 6, lane = t & 63;
    const int r0 = gb * 64 + (wave >> 1) * 32;
    const int c0 = (wave & 1) * 64;
    const int lrow = lane & 15, lk8 = (lane >> 4) * 8;
    const int row0 = min(r0 + lrow, N_NODES - 1);
    const int row1 = min(r0 + 16 + lrow, N_NODES - 1);
    const float* px0 = &X[(size_t)row0 * CH + lk8];
    const float* px1 = &X[(size_t)row1 * CH + lk8];
    const short* pw0 = &Wt[(size_t)(c0 + lrow) * CH + lk8];

    f32x4 acc[2][4] = {};

    float4 xa[2][2]; bf16x8 bb[4];
    xa[0][0] = *(const float4*)(px0); xa[0][1] = *(const float4*)(px0 + 4);
    xa[1][0] = *(const float4*)(px1); xa[1][1] = *(const float4*)(px1 + 4);
#pragma unroll
    for (int n = 0; n < 4; ++n) bb[n] = *(const bf16x8*)(pw0 + n * 16 * CH);

#pragma unroll
    for (int kk = 0; kk < 4; ++kk) {
        float4 xn[2][2]; bf16x8 bn[4];
        if (kk < 3) {
            const int ks = (kk + 1) * 32;
            xn[0][0] = *(const float4*)(px0 + ks); xn[0][1] = *(const float4*)(px0 + ks + 4);
            xn[1][0] = *(const float4*)(px1 + ks); xn[1][1] = *(const float4*)(px1 + ks + 4);
#pragma unroll
            for (int n = 0; n < 4; ++n) bn[n] = *(const bf16x8*)(pw0 + n * 16 * CH + ks);
        }
        bf16x8 a[2];
#pragma unroll
        for (int m = 0; m < 2; ++m) {
            a[m][0] = f2bf(xa[m][0].x); a[m][1] = f2bf(xa[m][0].y);
            a[m][2] = f2bf(xa[m][0].z); a[m][3] = f2bf(xa[m][0].w);
            a[m][4] = f2bf(xa[m][1].x); a[m][5] = f2bf(xa[m][1].y);
            a[m][6] = f2bf(xa[m][1].z); a[m][7] = f2bf(xa[m][1].w);
        }
#pragma unroll
        for (int m = 0; m < 2; ++m)
#pragma unroll
            for (int n = 0; n < 4; ++n)
                acc[m][n] = __builtin_amdgcn_mfma_f32_16x16x32_bf16(a[m], bb[n], acc[m][n], 0, 0, 0);
        if (kk < 3) {
#pragma unroll
            for (int m = 0; m < 2; ++m) { xa[m][0] = xn[m][0]; xa[m][1] = xn[m][1]; }
#pragma unroll
            for (int n = 0; n < 4; ++n) bb[n] = bn[n];
        }
    }

    // C/D layout: col = lane&15, row = (lane>>4)*4 + reg   [m89-verified]
#pragma unroll
    for (int m = 0; m < 2; ++m) {
#pragma unroll
        for (int reg = 0; reg < 4; ++reg) {
            const int row = r0 + m * 16 + (lane >> 4) * 4 + reg;
            if (row < N_NODES) {
#pragma unroll
                for (int n = 0; n < 4; ++n)
                    X0h[(size_t)row * CH + c0 + n * 16 + (lane & 15)] = f2bf(acc[m][n][reg]);
            }
        }
    }
}

// ====== FUSED phase 1: vcount(625) | ecount(125) | gemm(1563); 20KB LDS ======
__global__ __launch_bounds__(256) void k_phase1(const float* __restrict__ X,
                                                const short* __restrict__ Wt,
                                                short* __restrict__ X0h,
                                                const int* __restrict__ vertex,
                                                const int* __restrict__ edges,
                                                unsigned char* __restrict__ lrank_e,
                                                unsigned char* __restrict__ lrank_v5,
                                                unsigned int* __restrict__ blkcnt_e,
                                                unsigned int* __restrict__ blkcnt_v) {
    __shared__ unsigned int hist[EW];   // 20,480 B
    const int bid = blockIdx.x;
    const int t = threadIdx.x;

    if (bid < NRANGE * NCHUNK) {
        // ---- vcount: range r, chunk c (5,120 pairs; 20 iters -> short block) ----
        const int r = bid % NRANGE, c = bid / NRANGE;
        for (int i = t; i < VWR; i += 256) hist[i] = 0;
        __syncthreads();
        const int base = c * ECHUNK;
        const int vmin = r * VBIN_R;
        unsigned char* __restrict__ lr = lrank_v5 + (size_t)r * N_PAIRS;
#pragma unroll
        for (int it = 0; it < 20; ++it) {
            const int m = base + it * 256 + t;
            const int loc = vertex[m] - vmin;
            if ((unsigned)loc < (unsigned)VBIN_R) {
                const unsigned sh = (unsigned)(loc & 3) * 8u;
                unsigned old = atomicAdd(&hist[loc >> 2], 1u << sh);
                lr[m] = (unsigned char)((old >> sh) & 0xffu);
            }
        }
        __syncthreads();
        unsigned int* dst = &blkcnt_v[(size_t)(r * NCHUNK + c) * VWR];
        for (int w = t; w < VWR; w += 256) dst[w] = hist[w];
        return;
    }
    if (bid < NRANGE * NCHUNK + NCHUNK) {
        // ---- ecount: chunk c ----
        const int c = bid - NRANGE * NCHUNK;
        for (int i = t; i < EW; i += 256) hist[i] = 0;
        __syncthreads();
        const int base = c * ECHUNK;
#pragma unroll
        for (int it = 0; it < 20; ++it) {
            const int m = base + it * 256 + t;
            const int e = edges[m];
            const unsigned sh = (unsigned)(e & 3) * 8u;
            unsigned old = atomicAdd(&hist[e >> 2], 1u << sh);
            lrank_e[m] = (unsigned char)((old >> sh) & 0xffu);
        }
        __syncthreads();
        unsigned int* dst = &blkcnt_e[(size_t)c * EW];
        for (int w = t; w < EW; w += 256) dst[w] = hist[w];
        return;
    }
    gemm_body(bid - (NRANGE * NCHUNK + NCHUNK), X, Wt, X0h);
}

// ====== merged scan: per-word full-column exclusive prefix (replaces p1+p2o+p3)
//        + bin offsets via block-scan + one atomic per block ======
__global__ __launch_bounds__(256) void k_scan(unsigned int* __restrict__ blkcnt_e,
                                              unsigned int* __restrict__ blkcnt_v,
                                              int* __restrict__ off_e,
                                              int* __restrict__ end_e,
                                              int* __restrict__ off_v,
                                              int* __restrict__ end_v,
                                              int* __restrict__ totals) {
    __shared__ int s[256];
    __shared__ int base;
    const int bid = blockIdx.x, t = threadIdx.x;

    unsigned run = 0;
    int binbase = -1;
    int* off; int* end; int* total;

    if (bid < 20) {                       // edge: 20*256 = 5120 words exactly
        const int w = bid * 256 + t;
        unsigned int* p = blkcnt_e + w;
#pragma unroll 5
        for (int c = 0; c < NCHUNK; ++c) {
            const unsigned cc = *p;
            *p = run;
            run += cc;
            p += EW;
        }
        binbase = 4 * w;
        off = off_e; end = end_e; total = &totals[0];
    } else {                              // vertex: 5 ranges x 5000 words
        off = off_v; end = end_v; total = &totals[1];
        const int id = (bid - 20) * 256 + t;
        if (id < NRANGE * VWR) {
            const int r = id / VWR, w = id % VWR;
            unsigned int* p = blkcnt_v + (size_t)r * NCHUNK * VWR + w;
#pragma unroll 5
            for (int c = 0; c < NCHUNK; ++c) {
                const unsigned cc = *p;
                *p = run;
                run += cc;
                p += VWR;
            }
            binbase = r * VBIN_R + 4 * w;
        }
    }

    const int t0 = run & 255, t1 = (run >> 8) & 255,
              t2 = (run >> 16) & 255, t3 = run >> 24;
    const int mysum = t0 + t1 + t2 + t3;
    s[t] = mysum;
    __syncthreads();
    for (int d = 1; d < 256; d <<= 1) {
        int x = (t >= d) ? s[t - d] : 0;
        __syncthreads();
        s[t] += x;
        __syncthreads();
    }
    if (t == 0) base = atomicAdd(total, s[255]);
    __syncthreads();
    if (binbase >= 0) {
        int b = base + s[t] - mysum;
        off[binbase]     = b;           end[binbase]     = b + t0;  b += t0;
        off[binbase + 1] = b;           end[binbase + 1] = b + t1;  b += t1;
        off[binbase + 2] = b;           end[binbase + 2] = b + t2;  b += t2;
        off[binbase + 3] = b;           end[binbase + 3] = b + t3;
    }
}

// ------- atomic-free scatter -------
__global__ __launch_bounds__(256) void k_scatter(const int* __restrict__ vertex,
                                                 const int* __restrict__ edges,
                                                 const unsigned char* __restrict__ lrank_e,
                                                 const unsigned char* __restrict__ lrank_v5,
                                                 const unsigned int* __restrict__ blkcnt_e,
                                                 const unsigned int* __restrict__ blkcnt_v,
                                                 const int* __restrict__ off_e,
                                                 const int* __restrict__ off_v,
                                                 int* __restrict__ vlist_e,
                                                 int* __restrict__ elist_v) {
    const int m = blockIdx.x * 256 + threadIdx.x;
    const int e = edges[m];
    const int v = vertex[m];
    const int c = m / ECHUNK;
    const unsigned pe = blkcnt_e[(size_t)c * EW + (e >> 2)];
    const int er = (int)((pe >> ((unsigned)(e & 3) * 8u)) & 0xffu) + (int)lrank_e[m];
    const int r = v / VBIN_R, loc = v - r * VBIN_R;
    const unsigned pv = blkcnt_v[(size_t)(r * NCHUNK + c) * VWR + (loc >> 2)];
    const int vr = (int)((pv >> ((unsigned)(loc & 3) * 8u)) & 0xffu)
                 + (int)lrank_v5[(size_t)r * N_PAIRS + m];
    vlist_e[off_e[e] + er] = v;
    elist_v[off_v[v] + vr] = e;
}

// --------- per-edge: 16 lanes/edge, 2 edges/slot; full row per iteration ---------
__global__ __launch_bounds__(256) void k_edge(const short* __restrict__ X0h,
                                              const int* __restrict__ off_e,
                                              const int* __restrict__ end_e,
                                              const int* __restrict__ vlist,
                                              const float* __restrict__ att,
                                              short* __restrict__ Xeh,
                                              float* __restrict__ alpha_le) {
    const int t = threadIdx.x;
    const int slot = t >> 5, lane = t & 31;
    const int grp = lane >> 4, cl = lane & 15;     // channels [cl*8, cl*8+8)
    const int e = blockIdx.x * 16 + slot * 2 + grp;  // grid 1250 * 16 = 20000
    const int s = off_e[e], en = end_e[e];
    const int deg = en - s;
    const short* __restrict__ xb = X0h + cl * 8;

    float va[8] = {0.f, 0.f, 0.f, 0.f, 0.f, 0.f, 0.f, 0.f};
    for (int c0 = 0; c0 < deg; c0 += 16) {
        const int cn = min(16, deg - c0);
        int vl = (cl < cn) ? (vlist[s + c0 + cl] << 7) : 0;   // pre-scaled
#pragma unroll 4
        for (int j = 0; j < cn; ++j) {
            const int vo = __shfl(vl, grp * 16 + j, 32);      // within my 16-group
            uint4 xq = *(const uint4*)(xb + vo);
            va[0] += bflo(xq.x); va[1] += bfhi(xq.x);
            va[2] += bflo(xq.y); va[3] += bfhi(xq.y);
            va[4] += bflo(xq.z); va[5] += bfhi(xq.z);
            va[6] += bflo(xq.w); va[7] += bfhi(xq.w);
        }
    }

    const float invd = 1.0f / fmaxf((float)deg, 1.0f);
    bf16x8 xh;
    float xe[8];
#pragma unroll
    for (int i = 0; i < 8; ++i) { xe[i] = va[i] * invd; xh[i] = f2bf(xe[i]); }
    *(bf16x8*)&Xeh[(size_t)e * CH + cl * 8] = xh;

    const float4 a0 = *(const float4*)&att[cl * 8];
    const float4 a1 = *(const float4*)&att[cl * 8 + 4];
    float p = xe[0] * a0.x + xe[1] * a0.y + xe[2] * a0.z + xe[3] * a0.w
            + xe[4] * a1.x + xe[5] * a1.y + xe[6] * a1.z + xe[7] * a1.w;
    p += __shfl_xor(p, 1);
    p += __shfl_xor(p, 2);     // sum over the 4 lanes of this head group
    if ((cl & 3) == 0) {
        alpha_le[e * HEADS + (cl >> 2)] = (p > 0.f) ? p : 0.01f * p;
    }
}

// --------- per-vertex: 16 lanes/vertex, 2 vertices/slot; exp cached in LDS ---------
__global__ __launch_bounds__(256) void k_vertex(const short* __restrict__ X0h,
                                                const short* __restrict__ Xeh,
                                                const float* __restrict__ alpha_le,
                                                const int* __restrict__ off_v,
                                                const int* __restrict__ end_v,
                                                const int* __restrict__ elist,
                                                float* __restrict__ out) {
    const int t = threadIdx.x;
    const int slot = t >> 5, lane = t & 31;
    const int grp = lane >> 4, cl = lane & 15, h = cl >> 2;
    const int v = blockIdx.x * 16 + slot * 2 + grp;   // 6250*16 = 100000
    const int s = off_v[v], en = end_v[v];
    const int deg = en - s;

    __shared__ int   se[8][2][MAXDV];        // pre-scaled (e*CH)
    __shared__ float sa[8][2][MAXDV * HEADS];

    const short* __restrict__ xb = Xeh + cl * 8;

    float va[8] = {0.f, 0.f, 0.f, 0.f, 0.f, 0.f, 0.f, 0.f};
    if (deg <= MAXDV) {
        for (int j = cl; j < deg; j += 16) {
            const int e = elist[s + j];
            se[slot][grp][j] = e << 7;
            *(float4*)&sa[slot][grp][j << 2] = *(const float4*)&alpha_le[e * HEADS];
        }
        float mx = -INFINITY;
        for (int j = 0; j < deg; ++j) mx = fmaxf(mx, sa[slot][grp][(j << 2) + h]);
        float ssum = 0.f;
        for (int j = 0; j < deg; ++j) {
            const float p = __expf(sa[slot][grp][(j << 2) + h] - mx);
            sa[slot][grp][(j << 2) + h] = p;
            ssum += p;
        }
        const float inv = 1.0f / (ssum + 1e-8f);
        for (int j = 0; j < deg; ++j) {
            const float w = sa[slot][grp][(j << 2) + h] * inv;
            uint4 xq = *(const uint4*)(xb + se[slot][grp][j]);
            va[0] += w * bflo(xq.x); va[1] += w * bfhi(xq.x);
            va[2] += w * bflo(xq.y); va[3] += w * bfhi(xq.y);
            va[4] += w * bflo(xq.z); va[5] += w * bfhi(xq.z);
            va[6] += w * bflo(xq.w); va[7] += w * bfhi(xq.w);
        }
    } else {
        // global fallback (never taken for Poisson(6.4); correctness only)
        float mx = -INFINITY;
        for (int j = 0; j < deg; ++j) mx = fmaxf(mx, alpha_le[elist[s + j] * HEADS + h]);
        float ssum = 0.f;
        for (int j = 0; j < deg; ++j) ssum += __expf(alpha_le[elist[s + j] * HEADS + h] - mx);
        const float inv = 1.0f / (ssum + 1e-8f);
        for (int j = 0; j < deg; ++j) {
            const int e = elist[s + j];
            const float w = __expf(alpha_le[e * HEADS + h] - mx) * inv;
            uint4 xq = *(const uint4*)(xb + (e << 7));
            va[0] += w * bflo(xq.x); va[1] += w * bfhi(xq.x);
            va[2] += w * bflo(xq.y); va[3] += w * bfhi(xq.y);
            va[4] += w * bflo(xq.z); va[5] += w * bfhi(xq.z);
            va[6] += w * bflo(xq.w); va[7] += w * bfhi(xq.w);
        }
    }

    const uint4 rq = *(const uint4*)&X0h[(size_t)v * CH + cl * 8];
    float4 o0, o1;
    o0.x = va[0] + bflo(rq.x); o0.y = va[1] + bfhi(rq.x);
    o0.z = va[2] + bflo(rq.y); o0.w = va[3] + bfhi(rq.y);
    o1.x = va[4] + bflo(rq.z); o1.y = va[5] + bfhi(rq.z);
    o1.z = va[6] + bflo(rq.w); o1.w = va[7] + bfhi(rq.w);
    *(float4*)&out[(size_t)v * CH + cl * 8]     = o0;
    *(float4*)&out[(size_t)v * CH + cl * 8 + 4] = o1;
}

extern "C" void kernel_launch(void* const* d_in, const int* in_sizes, int n_in,
                              void* d_out, int out_size, void* d_ws, size_t ws_size,
                              hipStream_t stream) {
    const float* X      = (const float*)d_in[0];
    const float* W      = (const float*)d_in[1];
    const float* att    = (const float*)d_in[2];
    const int*   vertex = (const int*)d_in[3];
    const int*   edges  = (const int*)d_in[4];
    float* out = (float*)d_out;

    char* ws = (char*)d_ws;
    short* X0h      = (short*)(ws + OFF_X0H);
    short* Xeh      = (short*)(ws + OFF_XEH);
    unsigned char* lrank_e  = (unsigned char*)(ws + OFF_LRE);
    unsigned char* lrank_v5 = (unsigned char*)(ws + OFF_LRV5);
    unsigned int*  blkcnt_e = (unsigned int*)(ws + OFF_BLKE);
    unsigned int*  blkcnt_v = (unsigned int*)(ws + OFF_BLKV);
    short* Wt       = (short*)(ws + OFF_WT);
    float* alpha_le = (float*)(ws + OFF_ALPHA);
    int* off_e   = (int*)(ws + OFF_OFFE);
    int* end_e   = (int*)(ws + OFF_ENDE);
    int* off_v   = (int*)(ws + OFF_OFFV);
    int* end_v   = (int*)(ws + OFF_ENDV);
    int* vlist_e = (int*)(ws + OFF_PIDXE);
    int* elist_v = (int*)(ws + OFF_PIDXV);
    int* totals  = (int*)(ws + OFF_TOT);

    k_wprep<<<64, 256, 0, stream>>>(W, Wt, totals);
    k_phase1<<<NRANGE * NCHUNK + NCHUNK + NG_GEMM, 256, 0, stream>>>(
        X, Wt, X0h, vertex, edges, lrank_e, lrank_v5, blkcnt_e, blkcnt_v);
    k_scan<<<20 + 98, 256, 0, stream>>>(blkcnt_e, blkcnt_v, off_e, end_e,
                                        off_v, end_v, totals);
    k_scatter<<<N_PAIRS / 256, 256, 0, stream>>>(vertex, edges, lrank_e, lrank_v5,
                                                 blkcnt_e, blkcnt_v, off_e, off_v,
                                                 vlist_e, elist_v);
    k_edge<<<N_EDGES / 16, 256, 0, stream>>>(X0h, off_e, end_e, vlist_e, att, Xeh, alpha_le);
    k_vertex<<<N_NODES / 16, 256, 0, stream>>>(X0h, Xeh, alpha_le, off_v, end_v, elist_v, out);
}

// Round 20
// 142.073 us; speedup vs baseline: 1.0491x; 1.0167x over previous
//
#include <hip/hip_runtime.h>
#include <hip/hip_bf16.h>

#define N_NODES 100000
#define N_EDGES 20000
#define N_PAIRS 640000
#define CH 128      // HEADS * OUT_CH
#define HEADS 4
#define MAXDV 32    // per-vertex fast-path capacity (Poisson(6.4): max ~25)

#define NG2 782                 // ceil(100000/128) gemm blocks (2 row-tiles each)
#define NCHUNK 125              // pair chunks (both sides)
#define ECHUNK 5120             // pairs per chunk
#define EW 5120                 // edge hist words (20480 bins @ 4x8b) = 20.48KB
#define VWR 5000                // vertex hist words per range (20000 bins @ 4x8b)
#define NRANGE 5
#define VBIN_R 20000

// ---- workspace layout (bytes), all 16B-aligned ----
#define OFF_X0H   0UL           // 25,600,000
#define OFF_XEH   25600000UL    //  5,120,000
#define OFF_LRE   30720000UL    //    640,000 u8 (edge local rank)
#define OFF_LRV5  31360000UL    //  5*640,000 u8 (vertex local rank, per range)
#define OFF_BLKE  34560000UL    // 125*5120 u32 =  2,560,000
#define OFF_BLKV  37120000UL    // 625*5000 u32 = 12,500,000
#define OFF_WT    50222400UL    //     32,768
#define OFF_ALPHA 50255168UL    //    320,000
#define OFF_OFFE  50575168UL    //     81,920 (20480 i32)
#define OFF_ENDE  50657088UL    //     81,920
#define OFF_OFFV  50739008UL    //    400,000
#define OFF_ENDV  51139008UL    //    400,000
#define OFF_PIDXE 51539008UL    //  2,560,000 (VERTEX ids, edge-grouped)
#define OFF_PIDXV 54099008UL    //  2,560,000 (EDGE ids, vertex-grouped)
#define OFF_TOT   56659008UL    //          8 (zeroed by k_wprep each call)

typedef __attribute__((ext_vector_type(8))) short bf16x8;
typedef __attribute__((ext_vector_type(4))) float f32x4;

__device__ inline short f2bf(float f) {
    __hip_bfloat16 h = __float2bfloat16(f);   // RNE
    return reinterpret_cast<short&>(h);
}
__device__ inline float bflo(unsigned w) { return __uint_as_float(w << 16); }
__device__ inline float bfhi(unsigned w) { return __uint_as_float(w & 0xffff0000u); }

// ---- W prep: Wt[n][k] = bf16(W[k][n]); also zeroes totals (replaces memset) ----
__global__ __launch_bounds__(256) void k_wprep(const float* __restrict__ W,
                                               short* __restrict__ Wt,
                                               int* __restrict__ totals) {
    if (blockIdx.x == 0 && threadIdx.x < 2) totals[threadIdx.x] = 0;
    const int idx = blockIdx.x * 256 + threadIdx.x;   // 64 * 256
    const int n = idx >> 7, k = idx & 127;
    Wt[n * CH + k] = f2bf(W[k * CH + n]);
}

// ---- gemm body: 2 row-tiles (128 rows) per block; B-fragments loaded ONCE ----
__device__ inline void gemm_body2(int gb, const float* __restrict__ X,
                                  const short* __restrict__ Wt,
                                  short* __restrict__ X0h) {
    const int t = threadIdx.x;
    const int wave = t >> 6, lane = t & 63;
    const int c0 = (wave & 1) * 64;
    const int lrow = lane & 15, lk8 = (lane >> 4) * 8;
    const short* pw0 = &Wt[(size_t)(c0 + lrow) * CH + lk8];

    bf16x8 B[4][4];                      // [kstep][ncol], shared by both tiles
#pragma unroll
    for (int kk = 0; kk < 4; ++kk)
#pragma unroll
        for (int n = 0; n < 4; ++n)
            B[kk][n] = *(const bf16x8*)(pw0 + n * 16 * CH + kk * 32);

#pragma unroll
    for (int half = 0; half < 2; ++half) {
        const int r0 = gb * 128 + half * 64 + (wave >> 1) * 32;
        const int row0 = min(r0 + lrow, N_NODES - 1);
        const int row1 = min(r0 + 16 + lrow, N_NODES - 1);
        const float* px0 = &X[(size_t)row0 * CH + lk8];
        const float* px1 = &X[(size_t)row1 * CH + lk8];

        float4 xa0[4][2], xa1[4][2];     // full-depth A volley (one round trip)
#pragma unroll
        for (int kk = 0; kk < 4; ++kk) {
            xa0[kk][0] = *(const float4*)(px0 + kk * 32);
            xa0[kk][1] = *(const float4*)(px0 + kk * 32 + 4);
            xa1[kk][0] = *(const float4*)(px1 + kk * 32);
            xa1[kk][1] = *(const float4*)(px1 + kk * 32 + 4);
        }

        f32x4 acc[2][4] = {};
#pragma unroll
        for (int kk = 0; kk < 4; ++kk) {
            bf16x8 a[2];
            a[0][0] = f2bf(xa0[kk][0].x); a[0][1] = f2bf(xa0[kk][0].y);
            a[0][2] = f2bf(xa0[kk][0].z); a[0][3] = f2bf(xa0[kk][0].w);
            a[0][4] = f2bf(xa0[kk][1].x); a[0][5] = f2bf(xa0[kk][1].y);
            a[0][6] = f2bf(xa0[kk][1].z); a[0][7] = f2bf(xa0[kk][1].w);
            a[1][0] = f2bf(xa1[kk][0].x); a[1][1] = f2bf(xa1[kk][0].y);
            a[1][2] = f2bf(xa1[kk][0].z); a[1][3] = f2bf(xa1[kk][0].w);
            a[1][4] = f2bf(xa1[kk][1].x); a[1][5] = f2bf(xa1[kk][1].y);
            a[1][6] = f2bf(xa1[kk][1].z); a[1][7] = f2bf(xa1[kk][1].w);
#pragma unroll
            for (int m = 0; m < 2; ++m)
#pragma unroll
                for (int n = 0; n < 4; ++n)
                    acc[m][n] = __builtin_amdgcn_mfma_f32_16x16x32_bf16(a[m], B[kk][n], acc[m][n], 0, 0, 0);
        }

        // C/D layout: col = lane&15, row = (lane>>4)*4 + reg   [m89-verified]
#pragma unroll
        for (int m = 0; m < 2; ++m) {
#pragma unroll
            for (int reg = 0; reg < 4; ++reg) {
                const int row = r0 + m * 16 + (lane >> 4) * 4 + reg;
                if (row < N_NODES) {
#pragma unroll
                    for (int n = 0; n < 4; ++n)
                        X0h[(size_t)row * CH + c0 + n * 16 + (lane & 15)] = f2bf(acc[m][n][reg]);
                }
            }
        }
    }
}

// ====== FUSED phase 1: gemm(782, 2 tiles) | vcount(625) | ecount(125) ======
// grid = 1532 blocks < 7 blocks/CU * 256 CU -> single cohort, all resident.
__global__ __launch_bounds__(256) void k_phase1(const float* __restrict__ X,
                                                const short* __restrict__ Wt,
                                                short* __restrict__ X0h,
                                                const int* __restrict__ vertex,
                                                const int* __restrict__ edges,
                                                unsigned char* __restrict__ lrank_e,
                                                unsigned char* __restrict__ lrank_v5,
                                                unsigned int* __restrict__ blkcnt_e,
                                                unsigned int* __restrict__ blkcnt_v) {
    __shared__ unsigned int hist[EW];   // 20,480 B
    const int bid = blockIdx.x;
    const int t = threadIdx.x;

    if (bid < NG2) {
        gemm_body2(bid, X, Wt, X0h);
        return;
    }
    const int r2 = bid - NG2;
    if (r2 < NRANGE * NCHUNK) {
        // ---- vcount: range r, chunk c (5,120 pairs; 20 iters -> short block) ----
        const int r = r2 % NRANGE, c = r2 / NRANGE;
        for (int i = t; i < VWR; i += 256) hist[i] = 0;
        __syncthreads();
        const int base = c * ECHUNK;
        const int vmin = r * VBIN_R;
        unsigned char* __restrict__ lr = lrank_v5 + (size_t)r * N_PAIRS;
#pragma unroll
        for (int it = 0; it < 20; ++it) {
            const int m = base + it * 256 + t;
            const int loc = vertex[m] - vmin;
            if ((unsigned)loc < (unsigned)VBIN_R) {
                const unsigned sh = (unsigned)(loc & 3) * 8u;
                unsigned old = atomicAdd(&hist[loc >> 2], 1u << sh);
                lr[m] = (unsigned char)((old >> sh) & 0xffu);
            }
        }
        __syncthreads();
        unsigned int* dst = &blkcnt_v[(size_t)(r * NCHUNK + c) * VWR];
        for (int w = t; w < VWR; w += 256) dst[w] = hist[w];
        return;
    }
    // ---- ecount: chunk c ----
    const int c = r2 - NRANGE * NCHUNK;
    for (int i = t; i < EW; i += 256) hist[i] = 0;
    __syncthreads();
    const int base = c * ECHUNK;
#pragma unroll
    for (int it = 0; it < 20; ++it) {
        const int m = base + it * 256 + t;
        const int e = edges[m];
        const unsigned sh = (unsigned)(e & 3) * 8u;
        unsigned old = atomicAdd(&hist[e >> 2], 1u << sh);
        lrank_e[m] = (unsigned char)((old >> sh) & 0xffu);
    }
    __syncthreads();
    unsigned int* dst = &blkcnt_e[(size_t)c * EW];
    for (int w = t; w < EW; w += 256) dst[w] = hist[w];
}

// ====== merged scan: per-word full-column exclusive prefix + bin offsets ======
__global__ __launch_bounds__(256) void k_scan(unsigned int* __restrict__ blkcnt_e,
                                              unsigned int* __restrict__ blkcnt_v,
                                              int* __restrict__ off_e,
                                              int* __restrict__ end_e,
                                              int* __restrict__ off_v,
                                              int* __restrict__ end_v,
                                              int* __restrict__ totals) {
    __shared__ int s[256];
    __shared__ int base;
    const int bid = blockIdx.x, t = threadIdx.x;

    unsigned run = 0;
    int binbase = -1;
    int* off; int* end; int* total;

    if (bid < 20) {                       // edge: 20*256 = 5120 words exactly
        const int w = bid * 256 + t;
        unsigned int* p = blkcnt_e + w;
#pragma unroll 5
        for (int c = 0; c < NCHUNK; ++c) {
            const unsigned cc = *p;
            *p = run;
            run += cc;
            p += EW;
        }
        binbase = 4 * w;
        off = off_e; end = end_e; total = &totals[0];
    } else {                              // vertex: 5 ranges x 5000 words
        off = off_v; end = end_v; total = &totals[1];
        const int id = (bid - 20) * 256 + t;
        if (id < NRANGE * VWR) {
            const int r = id / VWR, w = id % VWR;
            unsigned int* p = blkcnt_v + (size_t)r * NCHUNK * VWR + w;
#pragma unroll 5
            for (int c = 0; c < NCHUNK; ++c) {
                const unsigned cc = *p;
                *p = run;
                run += cc;
                p += VWR;
            }
            binbase = r * VBIN_R + 4 * w;
        }
    }

    const int t0 = run & 255, t1 = (run >> 8) & 255,
              t2 = (run >> 16) & 255, t3 = run >> 24;
    const int mysum = t0 + t1 + t2 + t3;
    s[t] = mysum;
    __syncthreads();
    for (int d = 1; d < 256; d <<= 1) {
        int x = (t >= d) ? s[t - d] : 0;
        __syncthreads();
        s[t] += x;
        __syncthreads();
    }
    if (t == 0) base = atomicAdd(total, s[255]);
    __syncthreads();
    if (binbase >= 0) {
        int b = base + s[t] - mysum;
        off[binbase]     = b;           end[binbase]     = b + t0;  b += t0;
        off[binbase + 1] = b;           end[binbase + 1] = b + t1;  b += t1;
        off[binbase + 2] = b;           end[binbase + 2] = b + t2;  b += t2;
        off[binbase + 3] = b;           end[binbase + 3] = b + t3;
    }
}

// ------- atomic-free scatter -------
__global__ __launch_bounds__(256) void k_scatter(const int* __restrict__ vertex,
                                                 const int* __restrict__ edges,
                                                 const unsigned char* __restrict__ lrank_e,
                                                 const unsigned char* __restrict__ lrank_v5,
                                                 const unsigned int* __restrict__ blkcnt_e,
                                                 const unsigned int* __restrict__ blkcnt_v,
                                                 const int* __restrict__ off_e,
                                                 const int* __restrict__ off_v,
                                                 int* __restrict__ vlist_e,
                                                 int* __restrict__ elist_v) {
    const int m = blockIdx.x * 256 + threadIdx.x;
    const int e = edges[m];
    const int v = vertex[m];
    const int c = m / ECHUNK;
    const unsigned pe = blkcnt_e[(size_t)c * EW + (e >> 2)];
    const int er = (int)((pe >> ((unsigned)(e & 3) * 8u)) & 0xffu) + (int)lrank_e[m];
    const int r = v / VBIN_R, loc = v - r * VBIN_R;
    const unsigned pv = blkcnt_v[(size_t)(r * NCHUNK + c) * VWR + (loc >> 2)];
    const int vr = (int)((pv >> ((unsigned)(loc & 3) * 8u)) & 0xffu)
                 + (int)lrank_v5[(size_t)r * N_PAIRS + m];
    vlist_e[off_e[e] + er] = v;
    elist_v[off_v[v] + vr] = e;
}

// --------- per-edge: 16 lanes/edge, 2 edges/slot; full row per iteration ---------
__global__ __launch_bounds__(256) void k_edge(const short* __restrict__ X0h,
                                              const int* __restrict__ off_e,
                                              const int* __restrict__ end_e,
                                              const int* __restrict__ vlist,
                                              const float* __restrict__ att,
                                              short* __restrict__ Xeh,
                                              float* __restrict__ alpha_le) {
    const int t = threadIdx.x;
    const int slot = t >> 5, lane = t & 31;
    const int grp = lane >> 4, cl = lane & 15;     // channels [cl*8, cl*8+8)
    const int e = blockIdx.x * 16 + slot * 2 + grp;  // grid 1250 * 16 = 20000
    const int s = off_e[e], en = end_e[e];
    const int deg = en - s;
    const short* __restrict__ xb = X0h + cl * 8;

    float va[8] = {0.f, 0.f, 0.f, 0.f, 0.f, 0.f, 0.f, 0.f};
    for (int c0 = 0; c0 < deg; c0 += 16) {
        const int cn = min(16, deg - c0);
        int vl = (cl < cn) ? (vlist[s + c0 + cl] << 7) : 0;   // pre-scaled
#pragma unroll 4
        for (int j = 0; j < cn; ++j) {
            const int vo = __shfl(vl, grp * 16 + j, 32);      // within my 16-group
            uint4 xq = *(const uint4*)(xb + vo);
            va[0] += bflo(xq.x); va[1] += bfhi(xq.x);
            va[2] += bflo(xq.y); va[3] += bfhi(xq.y);
            va[4] += bflo(xq.z); va[5] += bfhi(xq.z);
            va[6] += bflo(xq.w); va[7] += bfhi(xq.w);
        }
    }

    const float invd = 1.0f / fmaxf((float)deg, 1.0f);
    bf16x8 xh;
    float xe[8];
#pragma unroll
    for (int i = 0; i < 8; ++i) { xe[i] = va[i] * invd; xh[i] = f2bf(xe[i]); }
    *(bf16x8*)&Xeh[(size_t)e * CH + cl * 8] = xh;

    const float4 a0 = *(const float4*)&att[cl * 8];
    const float4 a1 = *(const float4*)&att[cl * 8 + 4];
    float p = xe[0] * a0.x + xe[1] * a0.y + xe[2] * a0.z + xe[3] * a0.w
            + xe[4] * a1.x + xe[5] * a1.y + xe[6] * a1.z + xe[7] * a1.w;
    p += __shfl_xor(p, 1);
    p += __shfl_xor(p, 2);     // sum over the 4 lanes of this head group
    if ((cl & 3) == 0) {
        alpha_le[e * HEADS + (cl >> 2)] = (p > 0.f) ? p : 0.01f * p;
    }
}

// --------- per-vertex: 16 lanes/vertex, 2 vertices/slot; exp cached in LDS ---------
__global__ __launch_bounds__(256) void k_vertex(const short* __restrict__ X0h,
                                                const short* __restrict__ Xeh,
                                                const float* __restrict__ alpha_le,
                                                const int* __restrict__ off_v,
                                                const int* __restrict__ end_v,
                                                const int* __restrict__ elist,
                                                float* __restrict__ out) {
    const int t = threadIdx.x;
    const int slot = t >> 5, lane = t & 31;
    const int grp = lane >> 4, cl = lane & 15, h = cl >> 2;
    const int v = blockIdx.x * 16 + slot * 2 + grp;   // 6250*16 = 100000
    const int s = off_v[v], en = end_v[v];
    const int deg = en - s;

    __shared__ int   se[8][2][MAXDV];        // pre-scaled (e*CH)
    __shared__ float sa[8][2][MAXDV * HEADS];

    const short* __restrict__ xb = Xeh + cl * 8;

    float va[8] = {0.f, 0.f, 0.f, 0.f, 0.f, 0.f, 0.f, 0.f};
    if (deg <= MAXDV) {
        for (int j = cl; j < deg; j += 16) {
            const int e = elist[s + j];
            se[slot][grp][j] = e << 7;
            *(float4*)&sa[slot][grp][j << 2] = *(const float4*)&alpha_le[e * HEADS];
        }
        float mx = -INFINITY;
        for (int j = 0; j < deg; ++j) mx = fmaxf(mx, sa[slot][grp][(j << 2) + h]);
        float ssum = 0.f;
        for (int j = 0; j < deg; ++j) {
            const float p = __expf(sa[slot][grp][(j << 2) + h] - mx);
            sa[slot][grp][(j << 2) + h] = p;
            ssum += p;
        }
        const float inv = 1.0f / (ssum + 1e-8f);
        for (int j = 0; j < deg; ++j) {
            const float w = sa[slot][grp][(j << 2) + h] * inv;
            uint4 xq = *(const uint4*)(xb + se[slot][grp][j]);
            va[0] += w * bflo(xq.x); va[1] += w * bfhi(xq.x);
            va[2] += w * bflo(xq.y); va[3] += w * bfhi(xq.y);
            va[4] += w * bflo(xq.z); va[5] += w * bfhi(xq.z);
            va[6] += w * bflo(xq.w); va[7] += w * bfhi(xq.w);
        }
    } else {
        // global fallback (never taken for Poisson(6.4); correctness only)
        float mx = -INFINITY;
        for (int j = 0; j < deg; ++j) mx = fmaxf(mx, alpha_le[elist[s + j] * HEADS + h]);
        float ssum = 0.f;
        for (int j = 0; j < deg; ++j) ssum += __expf(alpha_le[elist[s + j] * HEADS + h] - mx);
        const float inv = 1.0f / (ssum + 1e-8f);
        for (int j = 0; j < deg; ++j) {
            const int e = elist[s + j];
            const float w = __expf(alpha_le[e * HEADS + h] - mx) * inv;
            uint4 xq = *(const uint4*)(xb + (e << 7));
            va[0] += w * bflo(xq.x); va[1] += w * bfhi(xq.x);
            va[2] += w * bflo(xq.y); va[3] += w * bfhi(xq.y);
            va[4] += w * bflo(xq.z); va[5] += w * bfhi(xq.z);
            va[6] += w * bflo(xq.w); va[7] += w * bfhi(xq.w);
        }
    }

    const uint4 rq = *(const uint4*)&X0h[(size_t)v * CH + cl * 8];
    float4 o0, o1;
    o0.x = va[0] + bflo(rq.x); o0.y = va[1] + bfhi(rq.x);
    o0.z = va[2] + bflo(rq.y); o0.w = va[3] + bfhi(rq.y);
    o1.x = va[4] + bflo(rq.z); o1.y = va[5] + bfhi(rq.z);
    o1.z = va[6] + bflo(rq.w); o1.w = va[7] + bfhi(rq.w);
    *(float4*)&out[(size_t)v * CH + cl * 8]     = o0;
    *(float4*)&out[(size_t)v * CH + cl * 8 + 4] = o1;
}

extern "C" void kernel_launch(void* const* d_in, const int* in_sizes, int n_in,
                              void* d_out, int out_size, void* d_ws, size_t ws_size,
                              hipStream_t stream) {
    const float* X      = (const float*)d_in[0];
    const float* W      = (const float*)d_in[1];
    const float* att    = (const float*)d_in[2];
    const int*   vertex = (const int*)d_in[3];
    const int*   edges  = (const int*)d_in[4];
    float* out = (float*)d_out;

    char* ws = (char*)d_ws;
    short* X0h      = (short*)(ws + OFF_X0H);
    short* Xeh      = (short*)(ws + OFF_XEH);
    unsigned char* lrank_e  = (unsigned char*)(ws + OFF_LRE);
    unsigned char* lrank_v5 = (unsigned char*)(ws + OFF_LRV5);
    unsigned int*  blkcnt_e = (unsigned int*)(ws + OFF_BLKE);
    unsigned int*  blkcnt_v = (unsigned int*)(ws + OFF_BLKV);
    short* Wt       = (short*)(ws + OFF_WT);
    float* alpha_le = (float*)(ws + OFF_ALPHA);
    int* off_e   = (int*)(ws + OFF_OFFE);
    int* end_e   = (int*)(ws + OFF_ENDE);
    int* off_v   = (int*)(ws + OFF_OFFV);
    int* end_v   = (int*)(ws + OFF_ENDV);
    int* vlist_e = (int*)(ws + OFF_PIDXE);
    int* elist_v = (int*)(ws + OFF_PIDXV);
    int* totals  = (int*)(ws + OFF_TOT);

    k_wprep<<<64, 256, 0, stream>>>(W, Wt, totals);
    k_phase1<<<NG2 + NRANGE * NCHUNK + NCHUNK, 256, 0, stream>>>(
        X, Wt, X0h, vertex, edges, lrank_e, lrank_v5, blkcnt_e, blkcnt_v);
    k_scan<<<20 + 98, 256, 0, stream>>>(blkcnt_e, blkcnt_v, off_e, end_e,
                                        off_v, end_v, totals);
    k_scatter<<<N_PAIRS / 256, 256, 0, stream>>>(vertex, edges, lrank_e, lrank_v5,
                                                 blkcnt_e, blkcnt_v, off_e, off_v,
                                                 vlist_e, elist_v);
    k_edge<<<N_EDGES / 16, 256, 0, stream>>>(X0h, off_e, end_e, vlist_e, att, Xeh, alpha_le);
    k_vertex<<<N_NODES / 16, 256, 0, stream>>>(X0h, Xeh, alpha_le, off_v, end_v, elist_v, out);
}

// Round 21
// 141.789 us; speedup vs baseline: 1.0512x; 1.0020x over previous
//
#include <hip/hip_runtime.h>
#include <hip/hip_bf16.h>

#define N_NODES 100000
#define N_EDGES 20000
#define N_PAIRS 640000
#define CH 128      // HEADS * OUT_CH
#define HEADS 4
#define MAXDV 32    // per-vertex fast-path capacity (Poisson(6.4): max ~25)

#define NG2 782                 // ceil(100000/128) gemm blocks (2 row-tiles each)
#define NCHUNK 125              // pair chunks (both sides)
#define ECHUNK 5120             // pairs per chunk
#define EW 5120                 // edge hist words (20480 bins @ 4x8b) = 20.48KB
#define VWR 5000                // vertex hist words per range (20000 bins @ 4x8b)
#define NRANGE 5
#define VBIN_R 20000

// ---- workspace layout (bytes), all 16B-aligned ----
#define OFF_X0H   0UL           // 25,600,000
#define OFF_XEH   25600000UL    //  5,120,000
#define OFF_LRE   30720000UL    //    640,000 u8 (edge local rank)
#define OFF_LRV5  31360000UL    //  5*640,000 u8 (vertex local rank, per range)
#define OFF_BLKE  34560000UL    // 125*5120 u32 =  2,560,000
#define OFF_BLKV  37120000UL    // 625*5000 u32 = 12,500,000
#define OFF_WT    50222400UL    //     32,768
#define OFF_ALPHA 50255168UL    //    320,000
#define OFF_OFFE  50575168UL    //     81,920 (20480 i32)
#define OFF_ENDE  50657088UL    //     81,920
#define OFF_OFFV  50739008UL    //    400,000
#define OFF_ENDV  51139008UL    //    400,000
#define OFF_PIDXE 51539008UL    //  2,560,000 (VERTEX ids, edge-grouped)
#define OFF_PIDXV 54099008UL    //  2,560,000 (EDGE ids, vertex-grouped)
#define OFF_TOT   56659008UL    //          8 (zeroed by k_wprep each call)

typedef __attribute__((ext_vector_type(8))) short bf16x8;
typedef __attribute__((ext_vector_type(4))) float f32x4;

__device__ inline short f2bf(float f) {
    __hip_bfloat16 h = __float2bfloat16(f);   // RNE
    return reinterpret_cast<short&>(h);
}
__device__ inline float bflo(unsigned w) { return __uint_as_float(w << 16); }
__device__ inline float bfhi(unsigned w) { return __uint_as_float(w & 0xffff0000u); }

// ---- W prep: Wt[n][k] = bf16(W[k][n]); also zeroes totals (replaces memset) ----
__global__ __launch_bounds__(256) void k_wprep(const float* __restrict__ W,
                                               short* __restrict__ Wt,
                                               int* __restrict__ totals) {
    if (blockIdx.x == 0 && threadIdx.x < 2) totals[threadIdx.x] = 0;
    const int idx = blockIdx.x * 256 + threadIdx.x;   // 64 * 256
    const int n = idx >> 7, k = idx & 127;
    Wt[n * CH + k] = f2bf(W[k * CH + n]);
}

// ---- gemm body: 2 row-tiles (128 rows) per block; B-fragments loaded ONCE ----
__device__ inline void gemm_body2(int gb, const float* __restrict__ X,
                                  const short* __restrict__ Wt,
                                  short* __restrict__ X0h) {
    const int t = threadIdx.x;
    const int wave = t >> 6, lane = t & 63;
    const int c0 = (wave & 1) * 64;
    const int lrow = lane & 15, lk8 = (lane >> 4) * 8;
    const short* pw0 = &Wt[(size_t)(c0 + lrow) * CH + lk8];

    bf16x8 B[4][4];                      // [kstep][ncol], shared by both tiles
#pragma unroll
    for (int kk = 0; kk < 4; ++kk)
#pragma unroll
        for (int n = 0; n < 4; ++n)
            B[kk][n] = *(const bf16x8*)(pw0 + n * 16 * CH + kk * 32);

#pragma unroll
    for (int half = 0; half < 2; ++half) {
        const int r0 = gb * 128 + half * 64 + (wave >> 1) * 32;
        const int row0 = min(r0 + lrow, N_NODES - 1);
        const int row1 = min(r0 + 16 + lrow, N_NODES - 1);
        const float* px0 = &X[(size_t)row0 * CH + lk8];
        const float* px1 = &X[(size_t)row1 * CH + lk8];

        float4 xa0[4][2], xa1[4][2];     // full-depth A volley (one round trip)
#pragma unroll
        for (int kk = 0; kk < 4; ++kk) {
            xa0[kk][0] = *(const float4*)(px0 + kk * 32);
            xa0[kk][1] = *(const float4*)(px0 + kk * 32 + 4);
            xa1[kk][0] = *(const float4*)(px1 + kk * 32);
            xa1[kk][1] = *(const float4*)(px1 + kk * 32 + 4);
        }

        f32x4 acc[2][4] = {};
#pragma unroll
        for (int kk = 0; kk < 4; ++kk) {
            bf16x8 a[2];
            a[0][0] = f2bf(xa0[kk][0].x); a[0][1] = f2bf(xa0[kk][0].y);
            a[0][2] = f2bf(xa0[kk][0].z); a[0][3] = f2bf(xa0[kk][0].w);
            a[0][4] = f2bf(xa0[kk][1].x); a[0][5] = f2bf(xa0[kk][1].y);
            a[0][6] = f2bf(xa0[kk][1].z); a[0][7] = f2bf(xa0[kk][1].w);
            a[1][0] = f2bf(xa1[kk][0].x); a[1][1] = f2bf(xa1[kk][0].y);
            a[1][2] = f2bf(xa1[kk][0].z); a[1][3] = f2bf(xa1[kk][0].w);
            a[1][4] = f2bf(xa1[kk][1].x); a[1][5] = f2bf(xa1[kk][1].y);
            a[1][6] = f2bf(xa1[kk][1].z); a[1][7] = f2bf(xa1[kk][1].w);
#pragma unroll
            for (int m = 0; m < 2; ++m)
#pragma unroll
                for (int n = 0; n < 4; ++n)
                    acc[m][n] = __builtin_amdgcn_mfma_f32_16x16x32_bf16(a[m], B[kk][n], acc[m][n], 0, 0, 0);
        }

        // C/D layout: col = lane&15, row = (lane>>4)*4 + reg   [m89-verified]
#pragma unroll
        for (int m = 0; m < 2; ++m) {
#pragma unroll
            for (int reg = 0; reg < 4; ++reg) {
                const int row = r0 + m * 16 + (lane >> 4) * 4 + reg;
                if (row < N_NODES) {
#pragma unroll
                    for (int n = 0; n < 4; ++n)
                        X0h[(size_t)row * CH + c0 + n * 16 + (lane & 15)] = f2bf(acc[m][n][reg]);
                }
            }
        }
    }
}

// ====== FUSED phase 1: gemm(782, 2 tiles) | vcount(625) | ecount(125) ======
__global__ __launch_bounds__(256) void k_phase1(const float* __restrict__ X,
                                                const short* __restrict__ Wt,
                                                short* __restrict__ X0h,
                                                const int* __restrict__ vertex,
                                                const int* __restrict__ edges,
                                                unsigned char* __restrict__ lrank_e,
                                                unsigned char* __restrict__ lrank_v5,
                                                unsigned int* __restrict__ blkcnt_e,
                                                unsigned int* __restrict__ blkcnt_v) {
    __shared__ unsigned int hist[EW];   // 20,480 B
    const int bid = blockIdx.x;
    const int t = threadIdx.x;

    if (bid < NG2) {
        gemm_body2(bid, X, Wt, X0h);
        return;
    }
    const int r2 = bid - NG2;
    if (r2 < NRANGE * NCHUNK) {
        // ---- vcount: range r, chunk c (5,120 pairs; 20 iters -> short block) ----
        const int r = r2 % NRANGE, c = r2 / NRANGE;
        for (int i = t; i < VWR; i += 256) hist[i] = 0;
        __syncthreads();
        const int base = c * ECHUNK;
        const int vmin = r * VBIN_R;
        unsigned char* __restrict__ lr = lrank_v5 + (size_t)r * N_PAIRS;
#pragma unroll
        for (int it = 0; it < 20; ++it) {
            const int m = base + it * 256 + t;
            const int loc = vertex[m] - vmin;
            if ((unsigned)loc < (unsigned)VBIN_R) {
                const unsigned sh = (unsigned)(loc & 3) * 8u;
                unsigned old = atomicAdd(&hist[loc >> 2], 1u << sh);
                lr[m] = (unsigned char)((old >> sh) & 0xffu);
            }
        }
        __syncthreads();
        unsigned int* dst = &blkcnt_v[(size_t)(r * NCHUNK + c) * VWR];
        for (int w = t; w < VWR; w += 256) dst[w] = hist[w];
        return;
    }
    // ---- ecount: chunk c ----
    const int c = r2 - NRANGE * NCHUNK;
    for (int i = t; i < EW; i += 256) hist[i] = 0;
    __syncthreads();
    const int base = c * ECHUNK;
#pragma unroll
    for (int it = 0; it < 20; ++it) {
        const int m = base + it * 256 + t;
        const int e = edges[m];
        const unsigned sh = (unsigned)(e & 3) * 8u;
        unsigned old = atomicAdd(&hist[e >> 2], 1u << sh);
        lrank_e[m] = (unsigned char)((old >> sh) & 0xffu);
    }
    __syncthreads();
    unsigned int* dst = &blkcnt_e[(size_t)c * EW];
    for (int w = t; w < EW; w += 256) dst[w] = hist[w];
}

// ====== merged scan: per-word full-column exclusive prefix + bin offsets ======
__global__ __launch_bounds__(256) void k_scan(unsigned int* __restrict__ blkcnt_e,
                                              unsigned int* __restrict__ blkcnt_v,
                                              int* __restrict__ off_e,
                                              int* __restrict__ end_e,
                                              int* __restrict__ off_v,
                                              int* __restrict__ end_v,
                                              int* __restrict__ totals) {
    __shared__ int s[256];
    __shared__ int base;
    const int bid = blockIdx.x, t = threadIdx.x;

    unsigned run = 0;
    int binbase = -1;
    int* off; int* end; int* total;

    if (bid < 20) {                       // edge: 20*256 = 5120 words exactly
        const int w = bid * 256 + t;
        unsigned int* p = blkcnt_e + w;
#pragma unroll 5
        for (int c = 0; c < NCHUNK; ++c) {
            const unsigned cc = *p;
            *p = run;
            run += cc;
            p += EW;
        }
        binbase = 4 * w;
        off = off_e; end = end_e; total = &totals[0];
    } else {                              // vertex: 5 ranges x 5000 words
        off = off_v; end = end_v; total = &totals[1];
        const int id = (bid - 20) * 256 + t;
        if (id < NRANGE * VWR) {
            const int r = id / VWR, w = id % VWR;
            unsigned int* p = blkcnt_v + (size_t)r * NCHUNK * VWR + w;
#pragma unroll 5
            for (int c = 0; c < NCHUNK; ++c) {
                const unsigned cc = *p;
                *p = run;
                run += cc;
                p += VWR;
            }
            binbase = r * VBIN_R + 4 * w;
        }
    }

    const int t0 = run & 255, t1 = (run >> 8) & 255,
              t2 = (run >> 16) & 255, t3 = run >> 24;
    const int mysum = t0 + t1 + t2 + t3;
    s[t] = mysum;
    __syncthreads();
    for (int d = 1; d < 256; d <<= 1) {
        int x = (t >= d) ? s[t - d] : 0;
        __syncthreads();
        s[t] += x;
        __syncthreads();
    }
    if (t == 0) base = atomicAdd(total, s[255]);
    __syncthreads();
    if (binbase >= 0) {
        int b = base + s[t] - mysum;
        off[binbase]     = b;           end[binbase]     = b + t0;  b += t0;
        off[binbase + 1] = b;           end[binbase + 1] = b + t1;  b += t1;
        off[binbase + 2] = b;           end[binbase + 2] = b + t2;  b += t2;
        off[binbase + 3] = b;           end[binbase + 3] = b + t3;
    }
}

// ------- atomic-free scatter -------
__global__ __launch_bounds__(256) void k_scatter(const int* __restrict__ vertex,
                                                 const int* __restrict__ edges,
                                                 const unsigned char* __restrict__ lrank_e,
                                                 const unsigned char* __restrict__ lrank_v5,
                                                 const unsigned int* __restrict__ blkcnt_e,
                                                 const unsigned int* __restrict__ blkcnt_v,
                                                 const int* __restrict__ off_e,
                                                 const int* __restrict__ off_v,
                                                 int* __restrict__ vlist_e,
                                                 int* __restrict__ elist_v) {
    const int m = blockIdx.x * 256 + threadIdx.x;
    const int e = edges[m];
    const int v = vertex[m];
    const int c = m / ECHUNK;
    const unsigned pe = blkcnt_e[(size_t)c * EW + (e >> 2)];
    const int er = (int)((pe >> ((unsigned)(e & 3) * 8u)) & 0xffu) + (int)lrank_e[m];
    const int r = v / VBIN_R, loc = v - r * VBIN_R;
    const unsigned pv = blkcnt_v[(size_t)(r * NCHUNK + c) * VWR + (loc >> 2)];
    const int vr = (int)((pv >> ((unsigned)(loc & 3) * 8u)) & 0xffu)
                 + (int)lrank_v5[(size_t)r * N_PAIRS + m];
    vlist_e[off_e[e] + er] = v;
    elist_v[off_v[v] + vr] = e;
}

// --------- per-edge: 16 lanes/edge, 2 edges/slot; 8-wide batched gathers ---------
__global__ __launch_bounds__(256) void k_edge(const short* __restrict__ X0h,
                                              const int* __restrict__ off_e,
                                              const int* __restrict__ end_e,
                                              const int* __restrict__ vlist,
                                              const float* __restrict__ att,
                                              short* __restrict__ Xeh,
                                              float* __restrict__ alpha_le) {
    const int t = threadIdx.x;
    const int slot = t >> 5, lane = t & 31;
    const int grp = lane >> 4, cl = lane & 15;     // channels [cl*8, cl*8+8)
    const int e = blockIdx.x * 16 + slot * 2 + grp;  // grid 1250 * 16 = 20000
    const int s = off_e[e], en = end_e[e];
    const int deg = en - s;
    const short* __restrict__ xb = X0h + cl * 8;

    float va[8] = {0.f, 0.f, 0.f, 0.f, 0.f, 0.f, 0.f, 0.f};
    for (int c0 = 0; c0 < deg; c0 += 16) {
        const int cn = min(16, deg - c0);
        int vl = (cl < cn) ? (vlist[s + c0 + cl] << 7) : 0;   // pre-scaled
        for (int j0 = 0; j0 < cn; j0 += 8) {
            uint4 xq[8];
#pragma unroll
            for (int u = 0; u < 8; ++u) {            // batch-issue 8 loads
                const int j = j0 + u;
                if (j < cn) xq[u] = *(const uint4*)(xb + __shfl(vl, grp * 16 + j, 32));
            }
#pragma unroll
            for (int u = 0; u < 8; ++u) {            // then consume
                const int j = j0 + u;
                if (j < cn) {
                    va[0] += bflo(xq[u].x); va[1] += bfhi(xq[u].x);
                    va[2] += bflo(xq[u].y); va[3] += bfhi(xq[u].y);
                    va[4] += bflo(xq[u].z); va[5] += bfhi(xq[u].z);
                    va[6] += bflo(xq[u].w); va[7] += bfhi(xq[u].w);
                }
            }
        }
    }

    const float invd = 1.0f / fmaxf((float)deg, 1.0f);
    bf16x8 xh;
    float xe[8];
#pragma unroll
    for (int i = 0; i < 8; ++i) { xe[i] = va[i] * invd; xh[i] = f2bf(xe[i]); }
    *(bf16x8*)&Xeh[(size_t)e * CH + cl * 8] = xh;

    const float4 a0 = *(const float4*)&att[cl * 8];
    const float4 a1 = *(const float4*)&att[cl * 8 + 4];
    float p = xe[0] * a0.x + xe[1] * a0.y + xe[2] * a0.z + xe[3] * a0.w
            + xe[4] * a1.x + xe[5] * a1.y + xe[6] * a1.z + xe[7] * a1.w;
    p += __shfl_xor(p, 1);
    p += __shfl_xor(p, 2);     // sum over the 4 lanes of this head group
    if ((cl & 3) == 0) {
        alpha_le[e * HEADS + (cl >> 2)] = (p > 0.f) ? p : 0.01f * p;
    }
}

// --------- per-vertex: 16 lanes/vertex, 2/slot; 8-wide batched weighted gathers ---------
__global__ __launch_bounds__(256) void k_vertex(const short* __restrict__ X0h,
                                                const short* __restrict__ Xeh,
                                                const float* __restrict__ alpha_le,
                                                const int* __restrict__ off_v,
                                                const int* __restrict__ end_v,
                                                const int* __restrict__ elist,
                                                float* __restrict__ out) {
    const int t = threadIdx.x;
    const int slot = t >> 5, lane = t & 31;
    const int grp = lane >> 4, cl = lane & 15, h = cl >> 2;
    const int v = blockIdx.x * 16 + slot * 2 + grp;   // 6250*16 = 100000
    const int s = off_v[v], en = end_v[v];
    const int deg = en - s;

    __shared__ int   se[8][2][MAXDV];        // pre-scaled (e*CH)
    __shared__ float sa[8][2][MAXDV * HEADS];

    const short* __restrict__ xb = Xeh + cl * 8;

    float va[8] = {0.f, 0.f, 0.f, 0.f, 0.f, 0.f, 0.f, 0.f};
    if (deg <= MAXDV) {
        for (int j = cl; j < deg; j += 16) {
            const int e = elist[s + j];
            se[slot][grp][j] = e << 7;
            *(float4*)&sa[slot][grp][j << 2] = *(const float4*)&alpha_le[e * HEADS];
        }
        float mx = -INFINITY;
        for (int j = 0; j < deg; ++j) mx = fmaxf(mx, sa[slot][grp][(j << 2) + h]);
        float ssum = 0.f;
        for (int j = 0; j < deg; ++j) {
            const float p = __expf(sa[slot][grp][(j << 2) + h] - mx);
            sa[slot][grp][(j << 2) + h] = p;
            ssum += p;
        }
        const float inv = 1.0f / (ssum + 1e-8f);
        // weighted gather: 8-wide batched issue (typical deg 6.4 -> one batch)
        for (int j0 = 0; j0 < deg; j0 += 8) {
            uint4 xq[8]; float w[8];
#pragma unroll
            for (int u = 0; u < 8; ++u) {
                const int j = j0 + u;
                if (j < deg) {
                    w[u] = sa[slot][grp][(j << 2) + h] * inv;
                    xq[u] = *(const uint4*)(xb + se[slot][grp][j]);
                }
            }
#pragma unroll
            for (int u = 0; u < 8; ++u) {
                const int j = j0 + u;
                if (j < deg) {
                    va[0] += w[u] * bflo(xq[u].x); va[1] += w[u] * bfhi(xq[u].x);
                    va[2] += w[u] * bflo(xq[u].y); va[3] += w[u] * bfhi(xq[u].y);
                    va[4] += w[u] * bflo(xq[u].z); va[5] += w[u] * bfhi(xq[u].z);
                    va[6] += w[u] * bflo(xq[u].w); va[7] += w[u] * bfhi(xq[u].w);
                }
            }
        }
    } else {
        // global fallback (never taken for Poisson(6.4); correctness only)
        float mx = -INFINITY;
        for (int j = 0; j < deg; ++j) mx = fmaxf(mx, alpha_le[elist[s + j] * HEADS + h]);
        float ssum = 0.f;
        for (int j = 0; j < deg; ++j) ssum += __expf(alpha_le[elist[s + j] * HEADS + h] - mx);
        const float inv = 1.0f / (ssum + 1e-8f);
        for (int j = 0; j < deg; ++j) {
            const int e = elist[s + j];
            const float w = __expf(alpha_le[e * HEADS + h] - mx) * inv;
            uint4 xq = *(const uint4*)(xb + (e << 7));
            va[0] += w * bflo(xq.x); va[1] += w * bfhi(xq.x);
            va[2] += w * bflo(xq.y); va[3] += w * bfhi(xq.y);
            va[4] += w * bflo(xq.z); va[5] += w * bfhi(xq.z);
            va[6] += w * bflo(xq.w); va[7] += w * bfhi(xq.w);
        }
    }

    const uint4 rq = *(const uint4*)&X0h[(size_t)v * CH + cl * 8];
    float4 o0, o1;
    o0.x = va[0] + bflo(rq.x); o0.y = va[1] + bfhi(rq.x);
    o0.z = va[2] + bflo(rq.y); o0.w = va[3] + bfhi(rq.y);
    o1.x = va[4] + bflo(rq.z); o1.y = va[5] + bfhi(rq.z);
    o1.z = va[6] + bflo(rq.w); o1.w = va[7] + bfhi(rq.w);
    *(float4*)&out[(size_t)v * CH + cl * 8]     = o0;
    *(float4*)&out[(size_t)v * CH + cl * 8 + 4] = o1;
}

extern "C" void kernel_launch(void* const* d_in, const int* in_sizes, int n_in,
                              void* d_out, int out_size, void* d_ws, size_t ws_size,
                              hipStream_t stream) {
    const float* X      = (const float*)d_in[0];
    const float* W      = (const float*)d_in[1];
    const float* att    = (const float*)d_in[2];
    const int*   vertex = (const int*)d_in[3];
    const int*   edges  = (const int*)d_in[4];
    float* out = (float*)d_out;

    char* ws = (char*)d_ws;
    short* X0h      = (short*)(ws + OFF_X0H);
    short* Xeh      = (short*)(ws + OFF_XEH);
    unsigned char* lrank_e  = (unsigned char*)(ws + OFF_LRE);
    unsigned char* lrank_v5 = (unsigned char*)(ws + OFF_LRV5);
    unsigned int*  blkcnt_e = (unsigned int*)(ws + OFF_BLKE);
    unsigned int*  blkcnt_v = (unsigned int*)(ws + OFF_BLKV);
    short* Wt       = (short*)(ws + OFF_WT);
    float* alpha_le = (float*)(ws + OFF_ALPHA);
    int* off_e   = (int*)(ws + OFF_OFFE);
    int* end_e   = (int*)(ws + OFF_ENDE);
    int* off_v   = (int*)(ws + OFF_OFFV);
    int* end_v   = (int*)(ws + OFF_ENDV);
    int* vlist_e = (int*)(ws + OFF_PIDXE);
    int* elist_v = (int*)(ws + OFF_PIDXV);
    int* totals  = (int*)(ws + OFF_TOT);

    k_wprep<<<64, 256, 0, stream>>>(W, Wt, totals);
    k_phase1<<<NG2 + NRANGE * NCHUNK + NCHUNK, 256, 0, stream>>>(
        X, Wt, X0h, vertex, edges, lrank_e, lrank_v5, blkcnt_e, blkcnt_v);
    k_scan<<<20 + 98, 256, 0, stream>>>(blkcnt_e, blkcnt_v, off_e, end_e,
                                        off_v, end_v, totals);
    k_scatter<<<N_PAIRS / 256, 256, 0, stream>>>(vertex, edges, lrank_e, lrank_v5,
                                                 blkcnt_e, blkcnt_v, off_e, off_v,
                                                 vlist_e, elist_v);
    k_edge<<<N_EDGES / 16, 256, 0, stream>>>(X0h, off_e, end_e, vlist_e, att, Xeh, alpha_le);
    k_vertex<<<N_NODES / 16, 256, 0, stream>>>(X0h, Xeh, alpha_le, off_v, end_v, elist_v, out);
}